// Round 8
// baseline (1050.600 us; speedup 1.0000x reference)
//
#include <hip/hip_runtime.h>
#include <hip/hip_bf16.h>

#define N_NODES 100000
#define N_EDGES 3200000
#define BSH 8                         // 256 nodes per bucket
#define NB 391                        // ceil(N_NODES / 256)
#define CNBLK2 2000                   // conv2_stream grid (8 blocks/CU co-resident)
#define NPB2 50                       // nodes per conv2_stream block (2000*50 = 100000)

typedef __hip_bfloat16 bf16;

// readlane broadcast: float from lane k (k compile-time constant)
#define RL(v, k) __int_as_float(__builtin_amdgcn_readlane(__float_as_int(v), (k)))

// ---- dtype-flexible load: flag==1 -> f32, flag==0 -> bf16 ----
__device__ __forceinline__ float loadF(const void* p, long long i, int isf32) {
    if (isf32) return ((const float*)p)[i];
    unsigned short v = ((const unsigned short*)p)[i];
    union { unsigned u; float f; } c;
    c.u = ((unsigned)v) << 16;
    return c.f;
}

// ---- packed edge: src (17 bits) << 15 | bf16-weight-bits (15 bits; w in [0,1)) ----
__device__ __forceinline__ unsigned packEdge(int s, float w) {
    bf16 b = __float2bfloat16(w);
    unsigned short bits = *(unsigned short*)&b;
    return ((unsigned)s << 15) | (unsigned)(bits & 0x7FFF);
}
__device__ __forceinline__ int edgeSrc(unsigned u) { return (int)(u >> 15); }
__device__ __forceinline__ float edgeW(unsigned u) {
    union { unsigned x; float f; } c;
    c.x = (u & 0x7FFFu) << 16;
    return c.f;
}

// ---- weight canonical layout (float offsets inside wts) ----
#define W_GAMMA 0
#define W_BETA 8
#define W_C1PW 16
#define W_C1PB 48
#define W_C1LW 56
#define W_C1LB 376
#define W_C1RW 440
#define W_C2PW 760
#define W_C2PB 4856
#define W_C2LW 4920
#define W_C2LB 9016
#define W_C2RW 9080
#define W_C3PW 13176
#define W_C3PB 17272
#define W_C3LW 17336
#define W_C3LB 17656
#define W_C3RW 17664

// ---------------- dtype detection ----------------
__global__ void detect_dtype(const void* ew, int* flag) {
    const unsigned short* u = (const unsigned short*)ew;
    int lane = threadIdx.x;
    int big = 0;
    for (int i = lane; i < 1024; i += 64) {
        unsigned short v = u[2 * i];
        int ex = (v >> 7) & 0xFF;
        if (ex >= 128) big++;
    }
#pragma unroll
    for (int o = 32; o; o >>= 1) big += __shfl_xor(big, o, 64);
    if (lane == 0) *flag = (big > 100) ? 1 : 0;
}

// ---------------- convert all weight tensors to canonical fp32 ----------------
__global__ void cvt_weights(const int* flag,
                            const void* p0, const void* p1, const void* p2, const void* p3,
                            const void* p4, const void* p5, const void* p6, const void* p7,
                            const void* p8, const void* p9, const void* p10, const void* p11,
                            const void* p12, const void* p13, const void* p14, const void* p15,
                            const void* p16, float* __restrict__ wts) {
    const void* ptrs[17] = {p0, p1, p2, p3, p4, p5, p6, p7, p8,
                            p9, p10, p11, p12, p13, p14, p15, p16};
    const int sz[17] = {5, 5, 25, 5, 320, 64, 320, 4096, 64,
                        4096, 64, 4096, 4096, 64, 320, 5, 320};
    const int off[17] = {W_GAMMA, W_BETA, W_C1PW, W_C1PB, W_C1LW, W_C1LB, W_C1RW,
                         W_C2PW, W_C2PB, W_C2LW, W_C2LB, W_C2RW,
                         W_C3PW, W_C3PB, W_C3LW, W_C3LB, W_C3RW};
    int t = blockIdx.x;
    int isf32 = *flag;
    for (int i = threadIdx.x; i < sz[t]; i += blockDim.x)
        wts[off[t] + i] = loadF(ptrs[t], i, isf32);
}

// ---------------- BN statistics ----------------
__global__ void bn_stats(const void* __restrict__ h, const int* __restrict__ flag,
                         float* __restrict__ stats) {
    int isf32 = *flag;
    float s[5] = {0, 0, 0, 0, 0}, q[5] = {0, 0, 0, 0, 0};
    int tid = blockIdx.x * blockDim.x + threadIdx.x;
    int stride = gridDim.x * blockDim.x;
    for (int i = tid; i < N_NODES; i += stride) {
#pragma unroll
        for (int f = 0; f < 5; f++) {
            float v = loadF(h, i * 5 + f, isf32);
            s[f] += v;
            q[f] += v * v;
        }
    }
#pragma unroll
    for (int f = 0; f < 5; f++) {
#pragma unroll
        for (int o = 32; o; o >>= 1) {
            s[f] += __shfl_xor(s[f], o, 64);
            q[f] += __shfl_xor(q[f], o, 64);
        }
    }
    __shared__ float ls[4][10];
    int wave = threadIdx.x >> 6, lane = threadIdx.x & 63;
    if (lane == 0) {
#pragma unroll
        for (int f = 0; f < 5; f++) { ls[wave][f] = s[f]; ls[wave][5 + f] = q[f]; }
    }
    __syncthreads();
    if (threadIdx.x < 10) {
        float v = ls[0][threadIdx.x] + ls[1][threadIdx.x] + ls[2][threadIdx.x] + ls[3][threadIdx.x];
        int idx = (threadIdx.x < 5) ? threadIdx.x : (threadIdx.x - 5 + 8);
        atomicAdd(&stats[idx], v);
    }
}

// ---------------- BN finalize + apply + conv1 projection (5->5), fused; xp1 padded to 8 ----
// pad cols 5..7 zeroed (conv1_gather's f>=5 lanes read them)
__global__ void bn_proj1(const void* __restrict__ h, const int* __restrict__ flag,
                         const float* __restrict__ stats, const float* __restrict__ wts,
                         float* __restrict__ xbn, float* __restrict__ xp1) {
    __shared__ float s_sc[5], s_sb[5];
    if (threadIdx.x < 5) {
        int f = threadIdx.x;
        float mean = stats[f] / (float)N_NODES;
        float var = stats[8 + f] / (float)N_NODES - mean * mean;
        float sc = wts[W_GAMMA + f] * rsqrtf(var + 1e-5f);
        s_sc[f] = sc;
        s_sb[f] = wts[W_BETA + f] - mean * sc;
    }
    __syncthreads();
    int isf32 = *flag;
    int i = blockIdx.x * blockDim.x + threadIdx.x;
    if (i >= N_NODES) return;
    float x[5];
#pragma unroll
    for (int f = 0; f < 5; f++)
        x[f] = loadF(h, i * 5 + f, isf32) * s_sc[f] + s_sb[f];
#pragma unroll
    for (int f = 0; f < 5; f++) xbn[i * 5 + f] = x[f];
#pragma unroll
    for (int j = 0; j < 5; j++) {
        float a = wts[W_C1PB + j];
#pragma unroll
        for (int k = 0; k < 5; k++) a += x[k] * wts[W_C1PW + k * 5 + j];
        xp1[i * 8 + j] = fmaxf(a, 0.f);
    }
#pragma unroll
    for (int j = 5; j < 8; j++) xp1[i * 8 + j] = 0.f;
}

// ---------------- CSR build, phase A1: bucket histogram ----------------
__global__ void __launch_bounds__(256) bucket_hist(const int* __restrict__ dst,
                                                   int* __restrict__ bucketCnt) {
    __shared__ int hcnt[NB];
    for (int i = threadIdx.x; i < NB; i += 256) hcnt[i] = 0;
    __syncthreads();
    int per = (N_EDGES + gridDim.x - 1) / gridDim.x;
    int s = blockIdx.x * per;
    int e = min(s + per, N_EDGES);
    for (int i = s + threadIdx.x; i < e; i += 256)
        atomicAdd(&hcnt[dst[i] >> BSH], 1);
    __syncthreads();
    for (int i = threadIdx.x; i < NB; i += 256)
        if (hcnt[i]) atomicAdd(&bucketCnt[i], hcnt[i]);
}

// ---------------- phase A2: exclusive scan of 391 bucket counts ----------------
__global__ void __launch_bounds__(512) bucket_scan(const int* __restrict__ bucketCnt,
                                                   int* __restrict__ bucketStart,
                                                   int* __restrict__ bucketCursor) {
    int tid = threadIdx.x, lane = tid & 63, w = tid >> 6;
    int v = (tid < NB) ? bucketCnt[tid] : 0;
    int sc = v;
#pragma unroll
    for (int o = 1; o < 64; o <<= 1) {
        int t = __shfl_up(sc, o, 64);
        if (lane >= o) sc += t;
    }
    __shared__ int ws[8];
    if (lane == 63) ws[w] = sc;
    __syncthreads();
    if (w == 0) {
        int wv = (lane < 8) ? ws[lane] : 0;
        int s2 = wv;
#pragma unroll
        for (int o = 1; o < 8; o <<= 1) {
            int t = __shfl_up(s2, o, 64);
            if (lane >= o) s2 += t;
        }
        if (lane < 8) ws[lane] = s2;
    }
    __syncthreads();
    int woff = w ? ws[w - 1] : 0;
    int ex = woff + sc - v;
    if (tid < NB) {
        bucketStart[tid] = ex;
        bucketCursor[tid] = ex;
    }
    if (tid == 0) bucketStart[NB] = N_EDGES;
}

// ---------------- phase A3: stage edges bucket-contiguously ({dst, packed}) ----------
__global__ void __launch_bounds__(256) bucket_stage(const int* __restrict__ src,
                                                    const int* __restrict__ dst,
                                                    const void* __restrict__ ew,
                                                    const int* __restrict__ flag,
                                                    int* __restrict__ bucketCursor,
                                                    uint2* __restrict__ stage) {
    __shared__ int hcnt[NB], cur[NB];
    int isf32 = *flag;
    for (int i = threadIdx.x; i < NB; i += 256) hcnt[i] = 0;
    __syncthreads();
    int per = (N_EDGES + gridDim.x - 1) / gridDim.x;
    int s = blockIdx.x * per;
    int e = min(s + per, N_EDGES);
    for (int i = s + threadIdx.x; i < e; i += 256)
        atomicAdd(&hcnt[dst[i] >> BSH], 1);
    __syncthreads();
    for (int i = threadIdx.x; i < NB; i += 256)
        cur[i] = hcnt[i] ? atomicAdd(&bucketCursor[i], hcnt[i]) : 0;
    __syncthreads();
    for (int i = s + threadIdx.x; i < e; i += 256) {
        int d = dst[i];
        int slot = atomicAdd(&cur[d >> BSH], 1);
        stage[slot] = make_uint2((unsigned)d, packEdge(src[i], loadF(ew, i, isf32)));
    }
}

// ---------------- phase B: per-bucket -> node-level CSR (start + perm) ----------------
__global__ void __launch_bounds__(256) bucket_place(const uint2* __restrict__ stage,
                                                    const int* __restrict__ bucketStart,
                                                    int* __restrict__ start,
                                                    unsigned* __restrict__ perm) {
    int b = blockIdx.x, tid = threadIdx.x;
    int base = bucketStart[b];
    int cnt = bucketStart[b + 1] - base;
    int n0 = b << BSH;
    int nn = min(256, N_NODES - n0);
    __shared__ int lcnt[256], loff[256], ws[4];
    lcnt[tid] = 0;
    __syncthreads();
    for (int i = tid; i < cnt; i += 256)
        atomicAdd(&lcnt[stage[base + i].x & 255], 1);
    __syncthreads();
    int lane = tid & 63, w = tid >> 6;
    int v = lcnt[tid];
    int sc = v;
#pragma unroll
    for (int o = 1; o < 64; o <<= 1) {
        int t = __shfl_up(sc, o, 64);
        if (lane >= o) sc += t;
    }
    if (lane == 63) ws[w] = sc;
    __syncthreads();
    int woff = 0;
    for (int k = 0; k < w; k++) woff += ws[k];
    loff[tid] = woff + sc - v;
    __syncthreads();
    if (tid < nn) start[n0 + tid] = base + loff[tid];
    if (b == 0 && tid == 0) start[N_NODES] = N_EDGES;
    lcnt[tid] = 0;
    __syncthreads();
    for (int i = tid; i < cnt; i += 256) {
        uint2 sv = stage[base + i];
        int l = sv.x & 255;
        int p = atomicAdd(&lcnt[l], 1);
        perm[base + loff[l] + p] = sv.y;
    }
}

// ---------------- sort_perm: per-node bitonic src-sort + K=4 phase offsets ------------
// Pure perf transform (sum is order-independent). Sorting the packed u32 sorts by src
// (src in high bits). deg>64: skip sort, all edges assigned phase 0 — still correct.
__global__ void __launch_bounds__(256) sort_perm(const int* __restrict__ start,
                                                 unsigned* __restrict__ perm,
                                                 ushort4* __restrict__ cums) {
    int lane = threadIdx.x & 63;
    int wid = (blockIdx.x * blockDim.x + threadIdx.x) >> 6;
    int nw = (gridDim.x * blockDim.x) >> 6;
    for (int node = wid; node < N_NODES; node += nw) {
        int e0 = start[node], e1 = start[node + 1];
        int deg = e1 - e0;
        if (deg > 64) {
            if (lane == 0)
                cums[node] = make_ushort4((unsigned short)deg, (unsigned short)deg,
                                          (unsigned short)deg, (unsigned short)deg);
            continue;
        }
        unsigned v = (lane < deg) ? perm[e0 + lane] : 0xFFFFFFFFu;
#pragma unroll
        for (int k = 2; k <= 64; k <<= 1) {
#pragma unroll
            for (int j = k >> 1; j > 0; j >>= 1) {
                unsigned o = __shfl_xor(v, j, 64);
                bool asc = ((lane & k) == 0);
                bool lower = ((lane & j) == 0);
                unsigned mn = min(v, o), mx = max(v, o);
                v = (asc == lower) ? mn : mx;
            }
        }
        if (lane < deg) perm[e0 + lane] = v;
        int srcn = (int)(v >> 15);
        bool valid = (lane < deg);
        int ph = (srcn >= 25000) + (srcn >= 50000) + (srcn >= 75000);
        unsigned long long b0 = __ballot(valid && ph <= 0);
        unsigned long long b1 = __ballot(valid && ph <= 1);
        unsigned long long b2 = __ballot(valid && ph <= 2);
        if (lane == 0)
            cums[node] = make_ushort4((unsigned short)__popcll(b0), (unsigned short)__popcll(b1),
                                      (unsigned short)__popcll(b2), (unsigned short)deg);
    }
}

// ---------------- conv1: 8-lanes-per-edge gather + lean epilogue -> x1 -----------------
__global__ void __launch_bounds__(256) conv1_gather(const float* __restrict__ xp1,
                                                    const float* __restrict__ xbn,
                                                    const int* __restrict__ start,
                                                    const unsigned* __restrict__ perm,
                                                    const float* __restrict__ wts,
                                                    float* __restrict__ x1) {
    int lane = threadIdx.x & 63;
    int slot = lane >> 3, f = lane & 7;
    int wid = __builtin_amdgcn_readfirstlane((blockIdx.x * blockDim.x + threadIdx.x) >> 6);
    int nw = (gridDim.x * blockDim.x) >> 6;
    float Wlw[5], Wrw[5];
#pragma unroll
    for (int k = 0; k < 5; k++) {
        Wlw[k] = wts[W_C1LW + k * 64 + lane];
        Wrw[k] = wts[W_C1RW + k * 64 + lane];
    }
    float lb = wts[W_C1LB + lane];
    for (int node = wid; node < N_NODES; node += nw) {
        int e0 = start[node], e1 = start[node + 1];
        float acc = 0.f;
        for (int eb = e0; eb < e1; eb += 32) {
            unsigned p[4];
#pragma unroll
            for (int q = 0; q < 4; q++) {
                int e = eb + q * 8 + slot;
                p[q] = (e < e1) ? perm[e] : 0u;   // sentinel: src 0, w 0
            }
            float v[4];
#pragma unroll
            for (int q = 0; q < 4; q++)
                v[q] = xp1[(size_t)(p[q] >> 15) * 8 + f];
#pragma unroll
            for (int q = 0; q < 4; q++)
                acc += v[q] * edgeW(p[q]);
        }
        acc += __shfl_xor(acc, 8, 64);
        acc += __shfl_xor(acc, 16, 64);
        acc += __shfl_xor(acc, 32, 64);
        float ic = 1.f / fmaxf((float)(e1 - e0), 1.f);
        float xb = (lane < 5) ? xbn[node * 5 + lane] : 0.f;
        float out = lb;
#pragma unroll
        for (int k = 0; k < 5; k++)
            out += RL(acc, k) * ic * Wlw[k] + RL(xb, k) * Wrw[k];
        float ss = out * out;
#pragma unroll
        for (int o = 32; o; o >>= 1) ss += __shfl_xor(ss, o, 64);
        float xv = fmaxf(out / fmaxf(sqrtf(ss), 1e-12f), 0.f);
        x1[(size_t)node * 64 + lane] = xv;
    }
}

// ---------------- proj2: y2 = relu(x1@c2pw+pb)@c2lw, node-blocked (16/wave) -----------
__global__ void __launch_bounds__(256) proj2_blocked(const float* __restrict__ x1,
                                                     const float* __restrict__ wts,
                                                     bf16* __restrict__ y2) {
    int lane = threadIdx.x & 63;
    int wid = (blockIdx.x * blockDim.x + threadIdx.x) >> 6;
    int nb = wid * 16;
    if (nb >= N_NODES) return;
    float xv[16];
#pragma unroll
    for (int n = 0; n < 16; n++) {
        int node = nb + n;
        xv[n] = (node < N_NODES) ? x1[(size_t)node * 64 + lane] : 0.f;
    }
    float a[16];
    float pb = wts[W_C2PB + lane];
#pragma unroll
    for (int n = 0; n < 16; n++) a[n] = pb;
#pragma unroll
    for (int c = 0; c < 4; c++) {
        float Wc[16];
#pragma unroll
        for (int j = 0; j < 16; j++) Wc[j] = wts[W_C2PW + (c * 16 + j) * 64 + lane];
#pragma unroll
        for (int n = 0; n < 16; n++) {
#pragma unroll
            for (int j = 0; j < 16; j++)
                a[n] += RL(xv[n], c * 16 + j) * Wc[j];
        }
    }
#pragma unroll
    for (int n = 0; n < 16; n++) a[n] = fmaxf(a[n], 0.f);
    float b[16];
#pragma unroll
    for (int n = 0; n < 16; n++) b[n] = 0.f;
#pragma unroll
    for (int c = 0; c < 4; c++) {
        float Wc[16];
#pragma unroll
        for (int j = 0; j < 16; j++) Wc[j] = wts[W_C2LW + (c * 16 + j) * 64 + lane];
#pragma unroll
        for (int n = 0; n < 16; n++) {
#pragma unroll
            for (int j = 0; j < 16; j++)
                b[n] += RL(a[n], c * 16 + j) * Wc[j];
        }
    }
#pragma unroll
    for (int n = 0; n < 16; n++) {
        int node = nb + n;
        if (node < N_NODES) y2[(size_t)node * 64 + lane] = __float2bfloat16(b[n]);
    }
}

// ---------------- conv2: virtual-stream phase-windowed gather -------------------------
// 2000 blocks x 50 nodes (12.8 KB LDS, <=64 VGPR target) -> 8 blocks/CU co-resident,
// 32 waves/CU (max). Each wave streams a fixed 12-deep batch ACROSS its nodes'
// phase-p segments (cursor walk is wave-uniform; per-slot local-node id byte-packed
// into ndp words; register accumulator flushed to LDS on node change). Pipeline depth
// no longer depends on segment length: 32 waves x 12 = 384 outstanding lines/CU
// (round 7: ~64). Phase windows (3.2 MB of y2 each) preserved; no barrier (round-5
// lesson), alignment via full co-residency. All array indices compile-time (rule:
// runtime-indexed arrays spill to scratch).
__global__ void __launch_bounds__(256, 8) conv2_stream(const bf16* __restrict__ y2,
                                                       const int* __restrict__ start,
                                                       const unsigned* __restrict__ perm,
                                                       const ushort4* __restrict__ cums,
                                                       const float* __restrict__ x1,
                                                       const float* __restrict__ wts,
                                                       float* __restrict__ x2) {
    __shared__ float sacc[NPB2 * 64];
    int tid = threadIdx.x, lane = tid & 63, w = tid >> 6;
    int nb0 = blockIdx.x * NPB2;
    for (int t = tid; t < NPB2 * 64; t += 256) sacc[t] = 0.f;
    __syncthreads();
#pragma unroll
    for (int p = 0; p < 4; p++) {
        int i = w;                 // local node cursor (wave owns i ≡ w mod 4)
        int e = 0, eh = 0;         // current segment [e, eh)
        int curload = -1;          // local id of segment being loaded
        int cur = -1;              // local id being accumulated
        float acc = 0.f;
        bool exhausted = false;
        while (true) {
            // ensure at least one real edge remains
            while (e >= eh) {
                if (i >= NPB2 || nb0 + i >= N_NODES) { exhausted = true; break; }
                int nodeg = nb0 + i;
                ushort4 c = cums[nodeg];
                int lo = (p == 0) ? 0 : ((p == 1) ? c.x : ((p == 2) ? c.y : c.z));
                int hi = (p == 0) ? c.x : ((p == 1) ? c.y : ((p == 2) ? c.z : c.w));
                int s0 = start[nodeg];
                e = s0 + lo; eh = s0 + hi;
                curload = i;
                i += 4;
            }
            if (exhausted) break;
            // fill 12 slots (compile-time indices; pads carry weight-0 + nd=curload)
            unsigned pk[12];
            unsigned ndp[3] = {0u, 0u, 0u};
#pragma unroll
            for (int u = 0; u < 12; u++) {
                if (e >= eh) {
                    while (e >= eh && i < NPB2 && nb0 + i < N_NODES) {
                        int nodeg = nb0 + i;
                        ushort4 c = cums[nodeg];
                        int lo = (p == 0) ? 0 : ((p == 1) ? c.x : ((p == 2) ? c.y : c.z));
                        int hi = (p == 0) ? c.x : ((p == 1) ? c.y : ((p == 2) ? c.z : c.w));
                        int s0 = start[nodeg];
                        e = s0 + lo; eh = s0 + hi;
                        curload = i;
                        i += 4;
                    }
                }
                if (e < eh) { pk[u] = perm[e]; e++; }
                else { pk[u] = 0u; exhausted = true; }
                ndp[u >> 2] |= ((unsigned)curload & 0xFFu) << ((u & 3) * 8);
            }
            // gather 12 (the latency window)
            float vv[12];
#pragma unroll
            for (int u = 0; u < 12; u++)
                vv[u] = __bfloat162float(y2[(size_t)(pk[u] >> 15) * 64 + lane]);
            // accumulate with uniform node-change flush
#pragma unroll
            for (int u = 0; u < 12; u++) {
                int nd = (int)((ndp[u >> 2] >> ((u & 3) * 8)) & 0xFFu);
                if (nd != cur) {
                    if (cur >= 0) sacc[cur * 64 + lane] += acc;
                    acc = 0.f;
                    cur = nd;
                }
                acc += vv[u] * edgeW(pk[u]);
            }
            if (exhausted) break;
        }
        if (cur >= 0) sacc[cur * 64 + lane] += acc;
    }
    // epilogue: root matmul + L2 norm (wave reads only its own rows; no sync needed —
    // rows written exclusively by owning wave after the zero-fill barrier)
    float lb = wts[W_C2LB + lane];
    for (int i = w; i < NPB2; i += 4) {
        int node = nb0 + i;
        if (node >= N_NODES) break;
        int deg = start[node + 1] - start[node];
        float acc = sacc[i * 64 + lane];
        float ic = 1.f / fmaxf((float)deg, 1.f);
        float xv = x1[(size_t)node * 64 + lane];
        float o0 = acc * ic + lb, o1 = 0.f, o2 = 0.f, o3 = 0.f;
#pragma unroll
        for (int k = 0; k < 64; k += 4) {
            o0 += RL(xv, k) * wts[W_C2RW + k * 64 + lane];
            o1 += RL(xv, k + 1) * wts[W_C2RW + (k + 1) * 64 + lane];
            o2 += RL(xv, k + 2) * wts[W_C2RW + (k + 2) * 64 + lane];
            o3 += RL(xv, k + 3) * wts[W_C2RW + (k + 3) * 64 + lane];
        }
        float out = (o0 + o1) + (o2 + o3);
        float ss = out * out;
#pragma unroll
        for (int o = 32; o; o >>= 1) ss += __shfl_xor(ss, o, 64);
        float v = out / fmaxf(sqrtf(ss), 1e-12f);
        x2[(size_t)node * 64 + lane] = fmaxf(v, 0.f);
    }
}

// ---------------- conv3 projection, W-in-VGPR: y3 = relu(x2@pw3+pb3)@lw3 (64->5, pad 8) --
__global__ void __launch_bounds__(256) proj3_reg(const float* __restrict__ x2,
                                                 const float* __restrict__ wts,
                                                 float* __restrict__ y3) {
    int lane = threadIdx.x & 63;
    int wid = __builtin_amdgcn_readfirstlane((blockIdx.x * blockDim.x + threadIdx.x) >> 6);
    int nw = (gridDim.x * blockDim.x) >> 6;
    float W1[64], Wl[5];
#pragma unroll
    for (int k = 0; k < 64; k++) W1[k] = wts[W_C3PW + k * 64 + lane];
#pragma unroll
    for (int j = 0; j < 5; j++) Wl[j] = wts[W_C3LW + lane * 5 + j];
    float pb = wts[W_C3PB + lane];
    for (int node = wid; node < N_NODES; node += nw) {
        float xv = x2[(size_t)node * 64 + lane];
        float a0 = pb, a1 = 0.f, a2 = 0.f, a3 = 0.f;
#pragma unroll
        for (int k = 0; k < 64; k += 4) {
            a0 += RL(xv, k) * W1[k];
            a1 += RL(xv, k + 1) * W1[k + 1];
            a2 += RL(xv, k + 2) * W1[k + 2];
            a3 += RL(xv, k + 3) * W1[k + 3];
        }
        float xp = fmaxf((a0 + a1) + (a2 + a3), 0.f);
#pragma unroll
        for (int j = 0; j < 5; j++) {
            float p = xp * Wl[j];
#pragma unroll
            for (int o = 32; o; o >>= 1) p += __shfl_xor(p, o, 64);
            if (lane == j) y3[(size_t)node * 8 + j] = p;
        }
    }
}

// ---------------- conv3: lane-parallel gather (padded rows) + epilogue (no relu) -------
__global__ void __launch_bounds__(256) conv3_fused(const float* __restrict__ y3,
                                                   const float* __restrict__ x2,
                                                   const int* __restrict__ start,
                                                   const unsigned* __restrict__ perm,
                                                   const float* __restrict__ wts,
                                                   const int* __restrict__ flag,
                                                   void* __restrict__ outp) {
    int lane = threadIdx.x & 63;
    int wid = __builtin_amdgcn_readfirstlane((blockIdx.x * blockDim.x + threadIdx.x) >> 6);
    int nw = (gridDim.x * blockDim.x) >> 6;
    float Wr[5];
#pragma unroll
    for (int j = 0; j < 5; j++) Wr[j] = wts[W_C3RW + lane * 5 + j];
    float lb3[5];
#pragma unroll
    for (int j = 0; j < 5; j++) lb3[j] = wts[W_C3LB + j];
    int isf32 = *flag;
    for (int node = wid; node < N_NODES; node += nw) {
        int e0 = start[node], e1 = start[node + 1];
        float s0 = 0, s1 = 0, s2 = 0, s3 = 0, s4 = 0;
        for (int eb = e0; eb < e1; eb += 64) {
            int e = eb + lane;
            if (e < e1) {
                unsigned p = perm[e];
                float w = edgeW(p);
                const float* row = y3 + (size_t)edgeSrc(p) * 8;
                float4 v4 = *(const float4*)row;
                float v5 = row[4];
                s0 += v4.x * w; s1 += v4.y * w; s2 += v4.z * w;
                s3 += v4.w * w; s4 += v5 * w;
            }
        }
#pragma unroll
        for (int o = 32; o; o >>= 1) {
            s0 += __shfl_xor(s0, o, 64);
            s1 += __shfl_xor(s1, o, 64);
            s2 += __shfl_xor(s2, o, 64);
            s3 += __shfl_xor(s3, o, 64);
            s4 += __shfl_xor(s4, o, 64);
        }
        float ic = 1.f / fmaxf((float)(e1 - e0), 1.f);
        float xv = x2[(size_t)node * 64 + lane];
        float m[5] = {s0 * ic, s1 * ic, s2 * ic, s3 * ic, s4 * ic};
        float r[5], ss = 0.f;
#pragma unroll
        for (int j = 0; j < 5; j++) {
            float p = xv * Wr[j];
#pragma unroll
            for (int o = 32; o; o >>= 1) p += __shfl_xor(p, o, 64);
            r[j] = p + m[j] + lb3[j];
            ss += r[j] * r[j];
        }
        float inv = 1.f / fmaxf(sqrtf(ss), 1e-12f);
#pragma unroll
        for (int j = 0; j < 5; j++) {
            if (lane == j) {
                float v = r[j] * inv;
                if (isf32) ((float*)outp)[node * 5 + j] = v;
                else ((bf16*)outp)[node * 5 + j] = __float2bfloat16(v);
            }
        }
    }
}

extern "C" void kernel_launch(void* const* d_in, const int* in_sizes, int n_in,
                              void* d_out, int out_size, void* d_ws, size_t ws_size,
                              hipStream_t stream) {
    const void* h = d_in[0];
    const int* ei = (const int*)d_in[1];
    const int* src = ei;
    const int* dst = ei + N_EDGES;
    const void* ew = d_in[2];

    float* W = (float*)d_ws;
    int* flag = (int*)W;                            // [0]
    float* stats = W + 16;                          // 32 floats
    float* wts = W + 64;                            // ~18k floats
    float* xbn = W + 20480;                         // N*5
    float* xp1 = xbn + N_NODES * 5;                 // N*8 padded (aliased by y3 later)
    int* startp = (int*)(xp1 + N_NODES * 8);        // N+1 ints (+pad)
    int* bucketCnt = startp + N_NODES + 64;         // NB ints
    int* bucketStart = bucketCnt + NB + 1;          // NB+1 ints
    int* bucketCursor = bucketStart + NB + 1;       // NB ints
    unsigned* perm = (unsigned*)(bucketCursor + NB + 62); // E u32 (packed src|w)
    float* x1 = (float*)(perm + N_EDGES);           // N*64 f32
    uint2* stage = (uint2*)x1;                      // E uint2 (dead before x1 written)
    bf16* y2 = (bf16*)(x1 + (size_t)N_NODES * 64);  // N*64 bf16
    float* x2 = x1;                                 // alias: per-thread same-idx read->write
    float* y3 = xp1;                                // alias: xp1 dead after conv1/proj2
    ushort4* cums = (ushort4*)(y2 + (size_t)N_NODES * 64);  // N ushort4 (800 KB)

    detect_dtype<<<1, 64, 0, stream>>>(ew, flag);
    cvt_weights<<<17, 256, 0, stream>>>(flag,
        d_in[3], d_in[4],
        d_in[5], d_in[6], d_in[7], d_in[8], d_in[9],
        d_in[10], d_in[11], d_in[12], d_in[13], d_in[14],
        d_in[15], d_in[16], d_in[17], d_in[18], d_in[19],
        wts);

    hipMemsetAsync(stats, 0, 32 * sizeof(float), stream);
    hipMemsetAsync(bucketCnt, 0, NB * sizeof(int), stream);

    bn_stats<<<200, 256, 0, stream>>>(h, flag, stats);
    bn_proj1<<<(N_NODES + 255) / 256, 256, 0, stream>>>(h, flag, stats, wts, xbn, xp1);

    // CSR build: bucketed two-phase (no global random-write-through)
    bucket_hist<<<512, 256, 0, stream>>>(dst, bucketCnt);
    bucket_scan<<<1, 512, 0, stream>>>(bucketCnt, bucketStart, bucketCursor);
    bucket_stage<<<512, 256, 0, stream>>>(src, dst, ew, flag, bucketCursor, stage);
    bucket_place<<<NB, 256, 0, stream>>>(stage, bucketStart, startp, perm);

    // per-node src-sort + phase offsets (perf-only transform)
    sort_perm<<<2048, 256, 0, stream>>>(startp, perm, cums);

    // conv1: 8-lane-per-edge gather (lean) then blocked projection to y2
    conv1_gather<<<4096, 256, 0, stream>>>(xp1, xbn, startp, perm, wts, x1);
    proj2_blocked<<<(N_NODES / 16 + 1 + 3) / 4, 256, 0, stream>>>(x1, wts, y2);

    // conv2: virtual-stream phase-windowed gather (L2 locality + full pipeline depth)
    conv2_stream<<<CNBLK2, 256, 0, stream>>>(y2, startp, perm, cums, x1, wts, x2);

    // conv3: projection then gather + epilogue
    proj3_reg<<<2048, 256, 0, stream>>>(x2, wts, y3);
    conv3_fused<<<2048, 256, 0, stream>>>(y3, x2, startp, perm, wts, flag, d_out);
}

// Round 9
// 828.929 us; speedup vs baseline: 1.2674x; 1.2674x over previous
//
#include <hip/hip_runtime.h>
#include <hip/hip_bf16.h>

#define N_NODES 100000
#define N_EDGES 3200000
#define BSH 8                         // 256 nodes per bucket
#define NB 391                        // ceil(N_NODES / 256)
#define CNBLK3 1000                   // conv2_phase grid (4 blocks/CU, all co-resident)
#define NPB3 100                      // nodes per conv2_phase block (1000*100 = 100000)
#define NOFFS 16000                   // CNBLK3 * 4 phases * 4 waves

typedef __hip_bfloat16 bf16;

// readlane broadcast: float from lane k (k compile-time constant)
#define RL(v, k) __int_as_float(__builtin_amdgcn_readlane(__float_as_int(v), (k)))

// ---- dtype-flexible load: flag==1 -> f32, flag==0 -> bf16 ----
__device__ __forceinline__ float loadF(const void* p, long long i, int isf32) {
    if (isf32) return ((const float*)p)[i];
    unsigned short v = ((const unsigned short*)p)[i];
    union { unsigned u; float f; } c;
    c.u = ((unsigned)v) << 16;
    return c.f;
}

// ---- packed edge: src (17 bits) << 15 | bf16-weight-bits (15 bits; w in [0,1)) ----
__device__ __forceinline__ unsigned packEdge(int s, float w) {
    bf16 b = __float2bfloat16(w);
    unsigned short bits = *(unsigned short*)&b;
    return ((unsigned)s << 15) | (unsigned)(bits & 0x7FFF);
}
__device__ __forceinline__ int edgeSrc(unsigned u) { return (int)(u >> 15); }
__device__ __forceinline__ float edgeW(unsigned u) {
    union { unsigned x; float f; } c;
    c.x = (u & 0x7FFFu) << 16;
    return c.f;
}

// ---- weight canonical layout (float offsets inside wts) ----
#define W_GAMMA 0
#define W_BETA 8
#define W_C1PW 16
#define W_C1PB 48
#define W_C1LW 56
#define W_C1LB 376
#define W_C1RW 440
#define W_C2PW 760
#define W_C2PB 4856
#define W_C2LW 4920
#define W_C2LB 9016
#define W_C2RW 9080
#define W_C3PW 13176
#define W_C3PB 17272
#define W_C3LW 17336
#define W_C3LB 17656
#define W_C3RW 17664

// ---------------- dtype detection ----------------
__global__ void detect_dtype(const void* ew, int* flag) {
    const unsigned short* u = (const unsigned short*)ew;
    int lane = threadIdx.x;
    int big = 0;
    for (int i = lane; i < 1024; i += 64) {
        unsigned short v = u[2 * i];
        int ex = (v >> 7) & 0xFF;
        if (ex >= 128) big++;
    }
#pragma unroll
    for (int o = 32; o; o >>= 1) big += __shfl_xor(big, o, 64);
    if (lane == 0) *flag = (big > 100) ? 1 : 0;
}

// ---------------- convert all weight tensors to canonical fp32 ----------------
__global__ void cvt_weights(const int* flag,
                            const void* p0, const void* p1, const void* p2, const void* p3,
                            const void* p4, const void* p5, const void* p6, const void* p7,
                            const void* p8, const void* p9, const void* p10, const void* p11,
                            const void* p12, const void* p13, const void* p14, const void* p15,
                            const void* p16, float* __restrict__ wts) {
    const void* ptrs[17] = {p0, p1, p2, p3, p4, p5, p6, p7, p8,
                            p9, p10, p11, p12, p13, p14, p15, p16};
    const int sz[17] = {5, 5, 25, 5, 320, 64, 320, 4096, 64,
                        4096, 64, 4096, 4096, 64, 320, 5, 320};
    const int off[17] = {W_GAMMA, W_BETA, W_C1PW, W_C1PB, W_C1LW, W_C1LB, W_C1RW,
                         W_C2PW, W_C2PB, W_C2LW, W_C2LB, W_C2RW,
                         W_C3PW, W_C3PB, W_C3LW, W_C3LB, W_C3RW};
    int t = blockIdx.x;
    int isf32 = *flag;
    for (int i = threadIdx.x; i < sz[t]; i += blockDim.x)
        wts[off[t] + i] = loadF(ptrs[t], i, isf32);
}

// ---------------- BN statistics ----------------
__global__ void bn_stats(const void* __restrict__ h, const int* __restrict__ flag,
                         float* __restrict__ stats) {
    int isf32 = *flag;
    float s[5] = {0, 0, 0, 0, 0}, q[5] = {0, 0, 0, 0, 0};
    int tid = blockIdx.x * blockDim.x + threadIdx.x;
    int stride = gridDim.x * blockDim.x;
    for (int i = tid; i < N_NODES; i += stride) {
#pragma unroll
        for (int f = 0; f < 5; f++) {
            float v = loadF(h, i * 5 + f, isf32);
            s[f] += v;
            q[f] += v * v;
        }
    }
#pragma unroll
    for (int f = 0; f < 5; f++) {
#pragma unroll
        for (int o = 32; o; o >>= 1) {
            s[f] += __shfl_xor(s[f], o, 64);
            q[f] += __shfl_xor(q[f], o, 64);
        }
    }
    __shared__ float ls[4][10];
    int wave = threadIdx.x >> 6, lane = threadIdx.x & 63;
    if (lane == 0) {
#pragma unroll
        for (int f = 0; f < 5; f++) { ls[wave][f] = s[f]; ls[wave][5 + f] = q[f]; }
    }
    __syncthreads();
    if (threadIdx.x < 10) {
        float v = ls[0][threadIdx.x] + ls[1][threadIdx.x] + ls[2][threadIdx.x] + ls[3][threadIdx.x];
        int idx = (threadIdx.x < 5) ? threadIdx.x : (threadIdx.x - 5 + 8);
        atomicAdd(&stats[idx], v);
    }
}

// ---------------- BN finalize + apply + conv1 projection (5->5), fused; xp1 padded to 8 ----
// pad cols 5..7 zeroed (conv1_gather's f>=5 lanes read them)
__global__ void bn_proj1(const void* __restrict__ h, const int* __restrict__ flag,
                         const float* __restrict__ stats, const float* __restrict__ wts,
                         float* __restrict__ xbn, float* __restrict__ xp1) {
    __shared__ float s_sc[5], s_sb[5];
    if (threadIdx.x < 5) {
        int f = threadIdx.x;
        float mean = stats[f] / (float)N_NODES;
        float var = stats[8 + f] / (float)N_NODES - mean * mean;
        float sc = wts[W_GAMMA + f] * rsqrtf(var + 1e-5f);
        s_sc[f] = sc;
        s_sb[f] = wts[W_BETA + f] - mean * sc;
    }
    __syncthreads();
    int isf32 = *flag;
    int i = blockIdx.x * blockDim.x + threadIdx.x;
    if (i >= N_NODES) return;
    float x[5];
#pragma unroll
    for (int f = 0; f < 5; f++)
        x[f] = loadF(h, i * 5 + f, isf32) * s_sc[f] + s_sb[f];
#pragma unroll
    for (int f = 0; f < 5; f++) xbn[i * 5 + f] = x[f];
#pragma unroll
    for (int j = 0; j < 5; j++) {
        float a = wts[W_C1PB + j];
#pragma unroll
        for (int k = 0; k < 5; k++) a += x[k] * wts[W_C1PW + k * 5 + j];
        xp1[i * 8 + j] = fmaxf(a, 0.f);
    }
#pragma unroll
    for (int j = 5; j < 8; j++) xp1[i * 8 + j] = 0.f;
}

// ---------------- CSR build, phase A1: bucket histogram ----------------
__global__ void __launch_bounds__(256) bucket_hist(const int* __restrict__ dst,
                                                   int* __restrict__ bucketCnt) {
    __shared__ int hcnt[NB];
    for (int i = threadIdx.x; i < NB; i += 256) hcnt[i] = 0;
    __syncthreads();
    int per = (N_EDGES + gridDim.x - 1) / gridDim.x;
    int s = blockIdx.x * per;
    int e = min(s + per, N_EDGES);
    for (int i = s + threadIdx.x; i < e; i += 256)
        atomicAdd(&hcnt[dst[i] >> BSH], 1);
    __syncthreads();
    for (int i = threadIdx.x; i < NB; i += 256)
        if (hcnt[i]) atomicAdd(&bucketCnt[i], hcnt[i]);
}

// ---------------- phase A2: exclusive scan of 391 bucket counts ----------------
__global__ void __launch_bounds__(512) bucket_scan(const int* __restrict__ bucketCnt,
                                                   int* __restrict__ bucketStart,
                                                   int* __restrict__ bucketCursor) {
    int tid = threadIdx.x, lane = tid & 63, w = tid >> 6;
    int v = (tid < NB) ? bucketCnt[tid] : 0;
    int sc = v;
#pragma unroll
    for (int o = 1; o < 64; o <<= 1) {
        int t = __shfl_up(sc, o, 64);
        if (lane >= o) sc += t;
    }
    __shared__ int ws[8];
    if (lane == 63) ws[w] = sc;
    __syncthreads();
    if (w == 0) {
        int wv = (lane < 8) ? ws[lane] : 0;
        int s2 = wv;
#pragma unroll
        for (int o = 1; o < 8; o <<= 1) {
            int t = __shfl_up(s2, o, 64);
            if (lane >= o) s2 += t;
        }
        if (lane < 8) ws[lane] = s2;
    }
    __syncthreads();
    int woff = w ? ws[w - 1] : 0;
    int ex = woff + sc - v;
    if (tid < NB) {
        bucketStart[tid] = ex;
        bucketCursor[tid] = ex;
    }
    if (tid == 0) bucketStart[NB] = N_EDGES;
}

// ---------------- phase A3: stage edges bucket-contiguously ({dst, packed}) ----------
__global__ void __launch_bounds__(256) bucket_stage(const int* __restrict__ src,
                                                    const int* __restrict__ dst,
                                                    const void* __restrict__ ew,
                                                    const int* __restrict__ flag,
                                                    int* __restrict__ bucketCursor,
                                                    uint2* __restrict__ stage) {
    __shared__ int hcnt[NB], cur[NB];
    int isf32 = *flag;
    for (int i = threadIdx.x; i < NB; i += 256) hcnt[i] = 0;
    __syncthreads();
    int per = (N_EDGES + gridDim.x - 1) / gridDim.x;
    int s = blockIdx.x * per;
    int e = min(s + per, N_EDGES);
    for (int i = s + threadIdx.x; i < e; i += 256)
        atomicAdd(&hcnt[dst[i] >> BSH], 1);
    __syncthreads();
    for (int i = threadIdx.x; i < NB; i += 256)
        cur[i] = hcnt[i] ? atomicAdd(&bucketCursor[i], hcnt[i]) : 0;
    __syncthreads();
    for (int i = s + threadIdx.x; i < e; i += 256) {
        int d = dst[i];
        int slot = atomicAdd(&cur[d >> BSH], 1);
        stage[slot] = make_uint2((unsigned)d, packEdge(src[i], loadF(ew, i, isf32)));
    }
}

// ---------------- phase B: per-bucket -> node-level CSR (start + perm) ----------------
__global__ void __launch_bounds__(256) bucket_place(const uint2* __restrict__ stage,
                                                    const int* __restrict__ bucketStart,
                                                    int* __restrict__ start,
                                                    unsigned* __restrict__ perm) {
    int b = blockIdx.x, tid = threadIdx.x;
    int base = bucketStart[b];
    int cnt = bucketStart[b + 1] - base;
    int n0 = b << BSH;
    int nn = min(256, N_NODES - n0);
    __shared__ int lcnt[256], loff[256], ws[4];
    lcnt[tid] = 0;
    __syncthreads();
    for (int i = tid; i < cnt; i += 256)
        atomicAdd(&lcnt[stage[base + i].x & 255], 1);
    __syncthreads();
    int lane = tid & 63, w = tid >> 6;
    int v = lcnt[tid];
    int sc = v;
#pragma unroll
    for (int o = 1; o < 64; o <<= 1) {
        int t = __shfl_up(sc, o, 64);
        if (lane >= o) sc += t;
    }
    if (lane == 63) ws[w] = sc;
    __syncthreads();
    int woff = 0;
    for (int k = 0; k < w; k++) woff += ws[k];
    loff[tid] = woff + sc - v;
    __syncthreads();
    if (tid < nn) start[n0 + tid] = base + loff[tid];
    if (b == 0 && tid == 0) start[N_NODES] = N_EDGES;
    lcnt[tid] = 0;
    __syncthreads();
    for (int i = tid; i < cnt; i += 256) {
        uint2 sv = stage[base + i];
        int l = sv.x & 255;
        int p = atomicAdd(&lcnt[l], 1);
        perm[base + loff[l] + p] = sv.y;
    }
}

// ---------------- sort_perm: per-node bitonic src-sort + K=4 phase offsets ------------
// Pure perf transform (sum is order-independent). Sorting the packed u32 sorts by src
// (src in high bits). deg>64: skip sort, all edges assigned phase 0 — still correct.
__global__ void __launch_bounds__(256) sort_perm(const int* __restrict__ start,
                                                 unsigned* __restrict__ perm,
                                                 ushort4* __restrict__ cums) {
    int lane = threadIdx.x & 63;
    int wid = (blockIdx.x * blockDim.x + threadIdx.x) >> 6;
    int nw = (gridDim.x * blockDim.x) >> 6;
    for (int node = wid; node < N_NODES; node += nw) {
        int e0 = start[node], e1 = start[node + 1];
        int deg = e1 - e0;
        if (deg > 64) {
            if (lane == 0)
                cums[node] = make_ushort4((unsigned short)deg, (unsigned short)deg,
                                          (unsigned short)deg, (unsigned short)deg);
            continue;
        }
        unsigned v = (lane < deg) ? perm[e0 + lane] : 0xFFFFFFFFu;
#pragma unroll
        for (int k = 2; k <= 64; k <<= 1) {
#pragma unroll
            for (int j = k >> 1; j > 0; j >>= 1) {
                unsigned o = __shfl_xor(v, j, 64);
                bool asc = ((lane & k) == 0);
                bool lower = ((lane & j) == 0);
                unsigned mn = min(v, o), mx = max(v, o);
                v = (asc == lower) ? mn : mx;
            }
        }
        if (lane < deg) perm[e0 + lane] = v;
        int srcn = (int)(v >> 15);
        bool valid = (lane < deg);
        int ph = (srcn >= 25000) + (srcn >= 50000) + (srcn >= 75000);
        unsigned long long b0 = __ballot(valid && ph <= 0);
        unsigned long long b1 = __ballot(valid && ph <= 1);
        unsigned long long b2 = __ballot(valid && ph <= 2);
        if (lane == 0)
            cums[node] = make_ushort4((unsigned short)__popcll(b0), (unsigned short)__popcll(b1),
                                      (unsigned short)__popcll(b2), (unsigned short)deg);
    }
}

// ---------------- phase_cnt: per-(block, phase, wave) edge counts ---------------------
__global__ void __launch_bounds__(256) phase_cnt(const ushort4* __restrict__ cums,
                                                 int* __restrict__ cnt) {
    int n = blockIdx.x * 256 + threadIdx.x;
    if (n >= N_NODES) return;
    ushort4 c = cums[n];
    int b = n / NPB3;
    int i = n % NPB3;
    int w = i & 3;
    int base = (b * 4) * 4 + w;   // index = (b*4 + p)*4 + w
    atomicAdd(&cnt[base + 0 * 4], (int)c.x);
    atomicAdd(&cnt[base + 1 * 4], (int)(c.y - c.x));
    atomicAdd(&cnt[base + 2 * 4], (int)(c.z - c.y));
    atomicAdd(&cnt[base + 3 * 4], (int)(c.w - c.z));
}

// ---------------- phase_scan: exclusive scan of 16000 counts (single block) -----------
__global__ void __launch_bounds__(256) phase_scan(const int* __restrict__ cnt,
                                                  int* __restrict__ offs) {
    __shared__ int ws2[4];
    __shared__ int sbase;
    if (threadIdx.x == 0) sbase = 0;
    __syncthreads();
    int tid = threadIdx.x, lane = tid & 63, w = tid >> 6;
    for (int c = 0; c < NOFFS; c += 256) {
        int idx = c + tid;
        int v = (idx < NOFFS) ? cnt[idx] : 0;
        int sc = v;
#pragma unroll
        for (int o = 1; o < 64; o <<= 1) {
            int t = __shfl_up(sc, o, 64);
            if (lane >= o) sc += t;
        }
        if (lane == 63) ws2[w] = sc;
        __syncthreads();
        int woff = 0;
        for (int k = 0; k < w; k++) woff += ws2[k];
        int ex = sbase + woff + sc - v;
        if (idx < NOFFS) offs[idx] = ex;
        __syncthreads();
        if (tid == 255) sbase = ex + v;
        __syncthreads();
    }
    if (threadIdx.x == 0) offs[NOFFS] = sbase;
}

// ---------------- phase_fill: materialize (block, phase, wave)-grouped edge stream ----
// perm2[j] = packed edge; ndloc[j] = local node id (0..99). Within each (b,p,w) run,
// nodes appear in increasing order -> conv2 accumulates in register, flushes on change.
__global__ void __launch_bounds__(256) phase_fill(const int* __restrict__ start,
                                                  const unsigned* __restrict__ perm,
                                                  const ushort4* __restrict__ cums,
                                                  const int* __restrict__ offs,
                                                  unsigned* __restrict__ perm2,
                                                  unsigned char* __restrict__ ndloc) {
    int b = blockIdx.x;
    int lane = threadIdx.x & 63, w = threadIdx.x >> 6;
    int c0 = offs[(b * 4 + 0) * 4 + w];
    int c1 = offs[(b * 4 + 1) * 4 + w];
    int c2 = offs[(b * 4 + 2) * 4 + w];
    int c3 = offs[(b * 4 + 3) * 4 + w];
    for (int i = w; i < NPB3; i += 4) {
        int n = b * NPB3 + i;
        ushort4 c = cums[n];
        int e0 = start[n];
        int l0 = c.x, l1 = c.y - c.x, l2 = c.z - c.y, l3 = c.w - c.z;
        for (int l = lane; l < l0; l += 64) {
            perm2[c0 + l] = perm[e0 + l];
            ndloc[c0 + l] = (unsigned char)i;
        }
        c0 += l0;
        for (int l = lane; l < l1; l += 64) {
            perm2[c1 + l] = perm[e0 + c.x + l];
            ndloc[c1 + l] = (unsigned char)i;
        }
        c1 += l1;
        for (int l = lane; l < l2; l += 64) {
            perm2[c2 + l] = perm[e0 + c.y + l];
            ndloc[c2 + l] = (unsigned char)i;
        }
        c2 += l2;
        for (int l = lane; l < l3; l += 64) {
            perm2[c3 + l] = perm[e0 + c.z + l];
            ndloc[c3 + l] = (unsigned char)i;
        }
        c3 += l3;
    }
}

// ---------------- conv1: 8-lanes-per-edge gather + lean epilogue -> x1 -----------------
__global__ void __launch_bounds__(256) conv1_gather(const float* __restrict__ xp1,
                                                    const float* __restrict__ xbn,
                                                    const int* __restrict__ start,
                                                    const unsigned* __restrict__ perm,
                                                    const float* __restrict__ wts,
                                                    float* __restrict__ x1) {
    int lane = threadIdx.x & 63;
    int slot = lane >> 3, f = lane & 7;
    int wid = __builtin_amdgcn_readfirstlane((blockIdx.x * blockDim.x + threadIdx.x) >> 6);
    int nw = (gridDim.x * blockDim.x) >> 6;
    float Wlw[5], Wrw[5];
#pragma unroll
    for (int k = 0; k < 5; k++) {
        Wlw[k] = wts[W_C1LW + k * 64 + lane];
        Wrw[k] = wts[W_C1RW + k * 64 + lane];
    }
    float lb = wts[W_C1LB + lane];
    for (int node = wid; node < N_NODES; node += nw) {
        int e0 = start[node], e1 = start[node + 1];
        float acc = 0.f;
        for (int eb = e0; eb < e1; eb += 32) {
            unsigned p[4];
#pragma unroll
            for (int q = 0; q < 4; q++) {
                int e = eb + q * 8 + slot;
                p[q] = (e < e1) ? perm[e] : 0u;   // sentinel: src 0, w 0
            }
            float v[4];
#pragma unroll
            for (int q = 0; q < 4; q++)
                v[q] = xp1[(size_t)(p[q] >> 15) * 8 + f];
#pragma unroll
            for (int q = 0; q < 4; q++)
                acc += v[q] * edgeW(p[q]);
        }
        acc += __shfl_xor(acc, 8, 64);
        acc += __shfl_xor(acc, 16, 64);
        acc += __shfl_xor(acc, 32, 64);
        float ic = 1.f / fmaxf((float)(e1 - e0), 1.f);
        float xb = (lane < 5) ? xbn[node * 5 + lane] : 0.f;
        float out = lb;
#pragma unroll
        for (int k = 0; k < 5; k++)
            out += RL(acc, k) * ic * Wlw[k] + RL(xb, k) * Wrw[k];
        float ss = out * out;
#pragma unroll
        for (int o = 32; o; o >>= 1) ss += __shfl_xor(ss, o, 64);
        float xv = fmaxf(out / fmaxf(sqrtf(ss), 1e-12f), 0.f);
        x1[(size_t)node * 64 + lane] = xv;
    }
}

// ---------------- proj2: y2 = relu(x1@c2pw+pb)@c2lw, node-blocked (16/wave) -----------
__global__ void __launch_bounds__(256) proj2_blocked(const float* __restrict__ x1,
                                                     const float* __restrict__ wts,
                                                     bf16* __restrict__ y2) {
    int lane = threadIdx.x & 63;
    int wid = (blockIdx.x * blockDim.x + threadIdx.x) >> 6;
    int nb = wid * 16;
    if (nb >= N_NODES) return;
    float xv[16];
#pragma unroll
    for (int n = 0; n < 16; n++) {
        int node = nb + n;
        xv[n] = (node < N_NODES) ? x1[(size_t)node * 64 + lane] : 0.f;
    }
    float a[16];
    float pb = wts[W_C2PB + lane];
#pragma unroll
    for (int n = 0; n < 16; n++) a[n] = pb;
#pragma unroll
    for (int c = 0; c < 4; c++) {
        float Wc[16];
#pragma unroll
        for (int j = 0; j < 16; j++) Wc[j] = wts[W_C2PW + (c * 16 + j) * 64 + lane];
#pragma unroll
        for (int n = 0; n < 16; n++) {
#pragma unroll
            for (int j = 0; j < 16; j++)
                a[n] += RL(xv[n], c * 16 + j) * Wc[j];
        }
    }
#pragma unroll
    for (int n = 0; n < 16; n++) a[n] = fmaxf(a[n], 0.f);
    float b[16];
#pragma unroll
    for (int n = 0; n < 16; n++) b[n] = 0.f;
#pragma unroll
    for (int c = 0; c < 4; c++) {
        float Wc[16];
#pragma unroll
        for (int j = 0; j < 16; j++) Wc[j] = wts[W_C2LW + (c * 16 + j) * 64 + lane];
#pragma unroll
        for (int n = 0; n < 16; n++) {
#pragma unroll
            for (int j = 0; j < 16; j++)
                b[n] += RL(a[n], c * 16 + j) * Wc[j];
        }
    }
#pragma unroll
    for (int n = 0; n < 16; n++) {
        int node = nb + n;
        if (node < N_NODES) y2[(size_t)node * 64 + lane] = __float2bfloat16(b[n]);
    }
}

// ---------------- conv2: phase-major gather over materialized stream ------------------
// 1000 blocks x 100 nodes (25.6 KB LDS, 4 waves) -> 4 blocks/CU, ALL co-resident
// (phase alignment via simultaneous launch; round-5 lesson: no spin barriers).
// Wave w streams its contiguous (b,p,w) runs of perm2 in STATIC 16-deep batches:
// 16 perm2 loads + 16 y2 gathers + 16 ndloc bytes, accumulate in register, flush to
// LDS row on node change (rows written only by owning wave -> no races). Straight-line
// code keeps pk/vv in VGPRs (round-8 lesson: dynamic cursor walks spill to scratch).
// Phase p confines gathers to y2 rows [p*25K,(p+1)*25K) = 3.2 MB (fits 4 MiB L2/XCD).
__global__ void __launch_bounds__(256, 4) conv2_phase(const bf16* __restrict__ y2,
                                                      const int* __restrict__ start,
                                                      const unsigned* __restrict__ perm2,
                                                      const unsigned char* __restrict__ ndloc,
                                                      const int* __restrict__ offs,
                                                      const float* __restrict__ x1,
                                                      const float* __restrict__ wts,
                                                      float* __restrict__ x2) {
    __shared__ float sacc[NPB3 * 64];
    int tid = threadIdx.x, lane = tid & 63, w = tid >> 6;
    int b = blockIdx.x;
    for (int t = tid; t < NPB3 * 64; t += 256) sacc[t] = 0.f;
    __syncthreads();
#pragma unroll
    for (int p = 0; p < 4; p++) {
        int j = offs[(b * 4 + p) * 4 + w];
        int jend = offs[(b * 4 + p) * 4 + w + 1];
        int cur = -1;
        float acc = 0.f;
        for (; j + 16 <= jend; j += 16) {
            unsigned pk[16];
#pragma unroll
            for (int u = 0; u < 16; u++) pk[u] = perm2[j + u];
            float vv[16];
#pragma unroll
            for (int u = 0; u < 16; u++)
                vv[u] = __bfloat162float(y2[(size_t)(pk[u] >> 15) * 64 + lane]);
#pragma unroll
            for (int u = 0; u < 16; u++) {
                int nd = (int)ndloc[j + u];
                if (nd != cur) {
                    if (cur >= 0) sacc[cur * 64 + lane] += acc;
                    acc = 0.f;
                    cur = nd;
                }
                acc += vv[u] * edgeW(pk[u]);
            }
        }
        for (; j < jend; j++) {
            unsigned pp = perm2[j];
            int nd = (int)ndloc[j];
            if (nd != cur) {
                if (cur >= 0) sacc[cur * 64 + lane] += acc;
                acc = 0.f;
                cur = nd;
            }
            acc += __bfloat162float(y2[(size_t)(pp >> 15) * 64 + lane]) * edgeW(pp);
        }
        if (cur >= 0) sacc[cur * 64 + lane] += acc;
    }
    // epilogue: root matmul + L2 norm (wave reads only rows it wrote; zero-fill barrier
    // above is the only sync needed)
    float lb = wts[W_C2LB + lane];
    for (int i = w; i < NPB3; i += 4) {
        int node = b * NPB3 + i;
        int deg = start[node + 1] - start[node];
        float acc = sacc[i * 64 + lane];
        float ic = 1.f / fmaxf((float)deg, 1.f);
        float xv = x1[(size_t)node * 64 + lane];
        float o0 = acc * ic + lb, o1 = 0.f, o2 = 0.f, o3 = 0.f;
#pragma unroll
        for (int k = 0; k < 64; k += 4) {
            o0 += RL(xv, k) * wts[W_C2RW + k * 64 + lane];
            o1 += RL(xv, k + 1) * wts[W_C2RW + (k + 1) * 64 + lane];
            o2 += RL(xv, k + 2) * wts[W_C2RW + (k + 2) * 64 + lane];
            o3 += RL(xv, k + 3) * wts[W_C2RW + (k + 3) * 64 + lane];
        }
        float out = (o0 + o1) + (o2 + o3);
        float ss = out * out;
#pragma unroll
        for (int o = 32; o; o >>= 1) ss += __shfl_xor(ss, o, 64);
        float v = out / fmaxf(sqrtf(ss), 1e-12f);
        x2[(size_t)node * 64 + lane] = fmaxf(v, 0.f);
    }
}

// ---------------- conv3 projection, W-in-VGPR: y3 = relu(x2@pw3+pb3)@lw3 (64->5, pad 8) --
__global__ void __launch_bounds__(256) proj3_reg(const float* __restrict__ x2,
                                                 const float* __restrict__ wts,
                                                 float* __restrict__ y3) {
    int lane = threadIdx.x & 63;
    int wid = __builtin_amdgcn_readfirstlane((blockIdx.x * blockDim.x + threadIdx.x) >> 6);
    int nw = (gridDim.x * blockDim.x) >> 6;
    float W1[64], Wl[5];
#pragma unroll
    for (int k = 0; k < 64; k++) W1[k] = wts[W_C3PW + k * 64 + lane];
#pragma unroll
    for (int j = 0; j < 5; j++) Wl[j] = wts[W_C3LW + lane * 5 + j];
    float pb = wts[W_C3PB + lane];
    for (int node = wid; node < N_NODES; node += nw) {
        float xv = x2[(size_t)node * 64 + lane];
        float a0 = pb, a1 = 0.f, a2 = 0.f, a3 = 0.f;
#pragma unroll
        for (int k = 0; k < 64; k += 4) {
            a0 += RL(xv, k) * W1[k];
            a1 += RL(xv, k + 1) * W1[k + 1];
            a2 += RL(xv, k + 2) * W1[k + 2];
            a3 += RL(xv, k + 3) * W1[k + 3];
        }
        float xp = fmaxf((a0 + a1) + (a2 + a3), 0.f);
#pragma unroll
        for (int j = 0; j < 5; j++) {
            float p = xp * Wl[j];
#pragma unroll
            for (int o = 32; o; o >>= 1) p += __shfl_xor(p, o, 64);
            if (lane == j) y3[(size_t)node * 8 + j] = p;
        }
    }
}

// ---------------- conv3: lane-parallel gather (padded rows) + epilogue (no relu) -------
__global__ void __launch_bounds__(256) conv3_fused(const float* __restrict__ y3,
                                                   const float* __restrict__ x2,
                                                   const int* __restrict__ start,
                                                   const unsigned* __restrict__ perm,
                                                   const float* __restrict__ wts,
                                                   const int* __restrict__ flag,
                                                   void* __restrict__ outp) {
    int lane = threadIdx.x & 63;
    int wid = __builtin_amdgcn_readfirstlane((blockIdx.x * blockDim.x + threadIdx.x) >> 6);
    int nw = (gridDim.x * blockDim.x) >> 6;
    float Wr[5];
#pragma unroll
    for (int j = 0; j < 5; j++) Wr[j] = wts[W_C3RW + lane * 5 + j];
    float lb3[5];
#pragma unroll
    for (int j = 0; j < 5; j++) lb3[j] = wts[W_C3LB + j];
    int isf32 = *flag;
    for (int node = wid; node < N_NODES; node += nw) {
        int e0 = start[node], e1 = start[node + 1];
        float s0 = 0, s1 = 0, s2 = 0, s3 = 0, s4 = 0;
        for (int eb = e0; eb < e1; eb += 64) {
            int e = eb + lane;
            if (e < e1) {
                unsigned p = perm[e];
                float w = edgeW(p);
                const float* row = y3 + (size_t)edgeSrc(p) * 8;
                float4 v4 = *(const float4*)row;
                float v5 = row[4];
                s0 += v4.x * w; s1 += v4.y * w; s2 += v4.z * w;
                s3 += v4.w * w; s4 += v5 * w;
            }
        }
#pragma unroll
        for (int o = 32; o; o >>= 1) {
            s0 += __shfl_xor(s0, o, 64);
            s1 += __shfl_xor(s1, o, 64);
            s2 += __shfl_xor(s2, o, 64);
            s3 += __shfl_xor(s3, o, 64);
            s4 += __shfl_xor(s4, o, 64);
        }
        float ic = 1.f / fmaxf((float)(e1 - e0), 1.f);
        float xv = x2[(size_t)node * 64 + lane];
        float m[5] = {s0 * ic, s1 * ic, s2 * ic, s3 * ic, s4 * ic};
        float r[5], ss = 0.f;
#pragma unroll
        for (int j = 0; j < 5; j++) {
            float p = xv * Wr[j];
#pragma unroll
            for (int o = 32; o; o >>= 1) p += __shfl_xor(p, o, 64);
            r[j] = p + m[j] + lb3[j];
            ss += r[j] * r[j];
        }
        float inv = 1.f / fmaxf(sqrtf(ss), 1e-12f);
#pragma unroll
        for (int j = 0; j < 5; j++) {
            if (lane == j) {
                float v = r[j] * inv;
                if (isf32) ((float*)outp)[node * 5 + j] = v;
                else ((bf16*)outp)[node * 5 + j] = __float2bfloat16(v);
            }
        }
    }
}

extern "C" void kernel_launch(void* const* d_in, const int* in_sizes, int n_in,
                              void* d_out, int out_size, void* d_ws, size_t ws_size,
                              hipStream_t stream) {
    const void* h = d_in[0];
    const int* ei = (const int*)d_in[1];
    const int* src = ei;
    const int* dst = ei + N_EDGES;
    const void* ew = d_in[2];

    float* W = (float*)d_ws;
    int* flag = (int*)W;                            // [0]
    float* stats = W + 16;                          // 32 floats
    float* wts = W + 64;                            // ~18k floats
    float* xbn = W + 20480;                         // N*5
    float* xp1 = xbn + N_NODES * 5;                 // N*8 padded (aliased: ndloc, then y3)
    int* startp = (int*)(xp1 + N_NODES * 8);        // N+1 ints (+pad)
    int* bucketCnt = startp + N_NODES + 64;         // NB ints
    int* bucketStart = bucketCnt + NB + 1;          // NB+1 ints
    int* bucketCursor = bucketStart + NB + 1;       // NB ints
    unsigned* perm = (unsigned*)(bucketCursor + NB + 62); // E u32 (packed src|w)
    float* x1 = (float*)(perm + N_EDGES);           // N*64 f32
    uint2* stage = (uint2*)x1;                      // E uint2 (dead before x1 written)
    bf16* y2 = (bf16*)(x1 + (size_t)N_NODES * 64);  // N*64 bf16
    float* x2 = x1;                                 // alias: per-thread same-idx read->write
    float* y3 = xp1;                                // alias: xp1/ndloc dead after conv2_phase
    ushort4* cums = (ushort4*)(y2 + (size_t)N_NODES * 64);  // N ushort4 (800 KB)
    int* cnt = (int*)(cums + N_NODES);              // NOFFS ints (64 KB)
    int* offs = cnt + NOFFS;                        // NOFFS+1 ints
    unsigned* perm2 = (unsigned*)(offs + NOFFS + 63); // E u32 (12.8 MB)
    unsigned char* ndloc = (unsigned char*)xp1;     // alias: E bytes == N*8*4 bytes exactly

    detect_dtype<<<1, 64, 0, stream>>>(ew, flag);
    cvt_weights<<<17, 256, 0, stream>>>(flag,
        d_in[3], d_in[4],
        d_in[5], d_in[6], d_in[7], d_in[8], d_in[9],
        d_in[10], d_in[11], d_in[12], d_in[13], d_in[14],
        d_in[15], d_in[16], d_in[17], d_in[18], d_in[19],
        wts);

    hipMemsetAsync(stats, 0, 32 * sizeof(float), stream);
    hipMemsetAsync(bucketCnt, 0, NB * sizeof(int), stream);
    hipMemsetAsync(cnt, 0, NOFFS * sizeof(int), stream);

    bn_stats<<<200, 256, 0, stream>>>(h, flag, stats);
    bn_proj1<<<(N_NODES + 255) / 256, 256, 0, stream>>>(h, flag, stats, wts, xbn, xp1);

    // CSR build: bucketed two-phase (no global random-write-through)
    bucket_hist<<<512, 256, 0, stream>>>(dst, bucketCnt);
    bucket_scan<<<1, 512, 0, stream>>>(bucketCnt, bucketStart, bucketCursor);
    bucket_stage<<<512, 256, 0, stream>>>(src, dst, ew, flag, bucketCursor, stage);
    bucket_place<<<NB, 256, 0, stream>>>(stage, bucketStart, startp, perm);

    // per-node src-sort + phase offsets, then per-(block,phase,wave) stream offsets
    sort_perm<<<2048, 256, 0, stream>>>(startp, perm, cums);
    phase_cnt<<<(N_NODES + 255) / 256, 256, 0, stream>>>(cums, cnt);
    phase_scan<<<1, 256, 0, stream>>>(cnt, offs);

    // conv1: 8-lane-per-edge gather (lean; reads xp1 -> xp1 dead after) then projection
    conv1_gather<<<4096, 256, 0, stream>>>(xp1, xbn, startp, perm, wts, x1);
    proj2_blocked<<<(N_NODES / 16 + 1 + 3) / 4, 256, 0, stream>>>(x1, wts, y2);

    // materialize phase-major stream (ndloc aliases dead xp1), then phase-windowed conv2
    phase_fill<<<CNBLK3, 256, 0, stream>>>(startp, perm, cums, offs, perm2, ndloc);
    conv2_phase<<<CNBLK3, 256, 0, stream>>>(y2, startp, perm2, ndloc, offs, x1, wts, x2);

    // conv3: projection then gather + epilogue (proj3 overwrites ndloc region with y3)
    proj3_reg<<<2048, 256, 0, stream>>>(x2, wts, y3);
    conv3_fused<<<2048, 256, 0, stream>>>(y3, x2, startp, perm, wts, flag, d_out);
}

// Round 12
// 574.252 us; speedup vs baseline: 1.8295x; 1.4435x over previous
//
#include <hip/hip_runtime.h>
#include <hip/hip_bf16.h>

#define N_NODES 100000
#define N_EDGES 3200000
#define BSH 8                         // 256 nodes per bucket
#define NB 391                        // ceil(N_NODES / 256)

typedef __hip_bfloat16 bf16;

// readlane broadcast: float from lane k (k compile-time constant)
#define RL(v, k) __int_as_float(__builtin_amdgcn_readlane(__float_as_int(v), (k)))

// ---- dtype-flexible load: flag==1 -> f32, flag==0 -> bf16 ----
__device__ __forceinline__ float loadF(const void* p, long long i, int isf32) {
    if (isf32) return ((const float*)p)[i];
    unsigned short v = ((const unsigned short*)p)[i];
    union { unsigned u; float f; } c;
    c.u = ((unsigned)v) << 16;
    return c.f;
}

// ---- packed edge: src (17 bits) << 15 | bf16-weight-bits (15 bits; w in [0,1)) ----
__device__ __forceinline__ unsigned packEdge(int s, float w) {
    bf16 b = __float2bfloat16(w);
    unsigned short bits = *(unsigned short*)&b;
    return ((unsigned)s << 15) | (unsigned)(bits & 0x7FFF);
}
__device__ __forceinline__ int edgeSrc(unsigned u) { return (int)(u >> 15); }
__device__ __forceinline__ float edgeW(unsigned u) {
    union { unsigned x; float f; } c;
    c.x = (u & 0x7FFFu) << 16;
    return c.f;
}

// ---- weight canonical layout (float offsets inside wts) ----
#define W_GAMMA 0
#define W_BETA 8
#define W_C1PW 16
#define W_C1PB 48
#define W_C1LW 56
#define W_C1LB 376
#define W_C1RW 440
#define W_C2PW 760
#define W_C2PB 4856
#define W_C2LW 4920
#define W_C2LB 9016
#define W_C2RW 9080
#define W_C3PW 13176
#define W_C3PB 17272
#define W_C3LW 17336
#define W_C3LB 17656
#define W_C3RW 17664

// ---------------- dtype detection ----------------
__global__ void detect_dtype(const void* ew, int* flag) {
    const unsigned short* u = (const unsigned short*)ew;
    int lane = threadIdx.x;
    int big = 0;
    for (int i = lane; i < 1024; i += 64) {
        unsigned short v = u[2 * i];
        int ex = (v >> 7) & 0xFF;
        if (ex >= 128) big++;
    }
#pragma unroll
    for (int o = 32; o; o >>= 1) big += __shfl_xor(big, o, 64);
    if (lane == 0) *flag = (big > 100) ? 1 : 0;
}

// ---------------- convert all weight tensors to canonical fp32 ----------------
__global__ void cvt_weights(const int* flag,
                            const void* p0, const void* p1, const void* p2, const void* p3,
                            const void* p4, const void* p5, const void* p6, const void* p7,
                            const void* p8, const void* p9, const void* p10, const void* p11,
                            const void* p12, const void* p13, const void* p14, const void* p15,
                            const void* p16, float* __restrict__ wts) {
    const void* ptrs[17] = {p0, p1, p2, p3, p4, p5, p6, p7, p8,
                            p9, p10, p11, p12, p13, p14, p15, p16};
    const int sz[17] = {5, 5, 25, 5, 320, 64, 320, 4096, 64,
                        4096, 64, 4096, 4096, 64, 320, 5, 320};
    const int off[17] = {W_GAMMA, W_BETA, W_C1PW, W_C1PB, W_C1LW, W_C1LB, W_C1RW,
                         W_C2PW, W_C2PB, W_C2LW, W_C2LB, W_C2RW,
                         W_C3PW, W_C3PB, W_C3LW, W_C3LB, W_C3RW};
    int t = blockIdx.x;
    int isf32 = *flag;
    for (int i = threadIdx.x; i < sz[t]; i += blockDim.x)
        wts[off[t] + i] = loadF(ptrs[t], i, isf32);
}

// ---------------- BN statistics ----------------
__global__ void bn_stats(const void* __restrict__ h, const int* __restrict__ flag,
                         float* __restrict__ stats) {
    int isf32 = *flag;
    float s[5] = {0, 0, 0, 0, 0}, q[5] = {0, 0, 0, 0, 0};
    int tid = blockIdx.x * blockDim.x + threadIdx.x;
    int stride = gridDim.x * blockDim.x;
    for (int i = tid; i < N_NODES; i += stride) {
#pragma unroll
        for (int f = 0; f < 5; f++) {
            float v = loadF(h, i * 5 + f, isf32);
            s[f] += v;
            q[f] += v * v;
        }
    }
#pragma unroll
    for (int f = 0; f < 5; f++) {
#pragma unroll
        for (int o = 32; o; o >>= 1) {
            s[f] += __shfl_xor(s[f], o, 64);
            q[f] += __shfl_xor(q[f], o, 64);
        }
    }
    __shared__ float ls[4][10];
    int wave = threadIdx.x >> 6, lane = threadIdx.x & 63;
    if (lane == 0) {
#pragma unroll
        for (int f = 0; f < 5; f++) { ls[wave][f] = s[f]; ls[wave][5 + f] = q[f]; }
    }
    __syncthreads();
    if (threadIdx.x < 10) {
        float v = ls[0][threadIdx.x] + ls[1][threadIdx.x] + ls[2][threadIdx.x] + ls[3][threadIdx.x];
        int idx = (threadIdx.x < 5) ? threadIdx.x : (threadIdx.x - 5 + 8);
        atomicAdd(&stats[idx], v);
    }
}

// ---------------- BN finalize + apply + conv1 projection (5->5), fused; xp1 padded to 8 ----
// pad cols 5..7 zeroed (conv1_gather's f>=5 lanes read them)
__global__ void bn_proj1(const void* __restrict__ h, const int* __restrict__ flag,
                         const float* __restrict__ stats, const float* __restrict__ wts,
                         float* __restrict__ xbn, float* __restrict__ xp1) {
    __shared__ float s_sc[5], s_sb[5];
    if (threadIdx.x < 5) {
        int f = threadIdx.x;
        float mean = stats[f] / (float)N_NODES;
        float var = stats[8 + f] / (float)N_NODES - mean * mean;
        float sc = wts[W_GAMMA + f] * rsqrtf(var + 1e-5f);
        s_sc[f] = sc;
        s_sb[f] = wts[W_BETA + f] - mean * sc;
    }
    __syncthreads();
    int isf32 = *flag;
    int i = blockIdx.x * blockDim.x + threadIdx.x;
    if (i >= N_NODES) return;
    float x[5];
#pragma unroll
    for (int f = 0; f < 5; f++)
        x[f] = loadF(h, i * 5 + f, isf32) * s_sc[f] + s_sb[f];
#pragma unroll
    for (int f = 0; f < 5; f++) xbn[i * 5 + f] = x[f];
#pragma unroll
    for (int j = 0; j < 5; j++) {
        float a = wts[W_C1PB + j];
#pragma unroll
        for (int k = 0; k < 5; k++) a += x[k] * wts[W_C1PW + k * 5 + j];
        xp1[i * 8 + j] = fmaxf(a, 0.f);
    }
#pragma unroll
    for (int j = 5; j < 8; j++) xp1[i * 8 + j] = 0.f;
}

// ---------------- CSR build, phase A1: bucket histogram ----------------
__global__ void __launch_bounds__(256) bucket_hist(const int* __restrict__ dst,
                                                   int* __restrict__ bucketCnt) {
    __shared__ int hcnt[NB];
    for (int i = threadIdx.x; i < NB; i += 256) hcnt[i] = 0;
    __syncthreads();
    int per = (N_EDGES + gridDim.x - 1) / gridDim.x;
    int s = blockIdx.x * per;
    int e = min(s + per, N_EDGES);
    for (int i = s + threadIdx.x; i < e; i += 256)
        atomicAdd(&hcnt[dst[i] >> BSH], 1);
    __syncthreads();
    for (int i = threadIdx.x; i < NB; i += 256)
        if (hcnt[i]) atomicAdd(&bucketCnt[i], hcnt[i]);
}

// ---------------- phase A2: exclusive scan of 391 bucket counts ----------------
__global__ void __launch_bounds__(512) bucket_scan(const int* __restrict__ bucketCnt,
                                                   int* __restrict__ bucketStart,
                                                   int* __restrict__ bucketCursor) {
    int tid = threadIdx.x, lane = tid & 63, w = tid >> 6;
    int v = (tid < NB) ? bucketCnt[tid] : 0;
    int sc = v;
#pragma unroll
    for (int o = 1; o < 64; o <<= 1) {
        int t = __shfl_up(sc, o, 64);
        if (lane >= o) sc += t;
    }
    __shared__ int ws[8];
    if (lane == 63) ws[w] = sc;
    __syncthreads();
    if (w == 0) {
        int wv = (lane < 8) ? ws[lane] : 0;
        int s2 = wv;
#pragma unroll
        for (int o = 1; o < 8; o <<= 1) {
            int t = __shfl_up(s2, o, 64);
            if (lane >= o) s2 += t;
        }
        if (lane < 8) ws[lane] = s2;
    }
    __syncthreads();
    int woff = w ? ws[w - 1] : 0;
    int ex = woff + sc - v;
    if (tid < NB) {
        bucketStart[tid] = ex;
        bucketCursor[tid] = ex;
    }
    if (tid == 0) bucketStart[NB] = N_EDGES;
}

// ---------------- phase A3: stage edges bucket-contiguously ({dst, packed}) ----------
__global__ void __launch_bounds__(256) bucket_stage(const int* __restrict__ src,
                                                    const int* __restrict__ dst,
                                                    const void* __restrict__ ew,
                                                    const int* __restrict__ flag,
                                                    int* __restrict__ bucketCursor,
                                                    uint2* __restrict__ stage) {
    __shared__ int hcnt[NB], cur[NB];
    int isf32 = *flag;
    for (int i = threadIdx.x; i < NB; i += 256) hcnt[i] = 0;
    __syncthreads();
    int per = (N_EDGES + gridDim.x - 1) / gridDim.x;
    int s = blockIdx.x * per;
    int e = min(s + per, N_EDGES);
    for (int i = s + threadIdx.x; i < e; i += 256)
        atomicAdd(&hcnt[dst[i] >> BSH], 1);
    __syncthreads();
    for (int i = threadIdx.x; i < NB; i += 256)
        cur[i] = hcnt[i] ? atomicAdd(&bucketCursor[i], hcnt[i]) : 0;
    __syncthreads();
    for (int i = s + threadIdx.x; i < e; i += 256) {
        int d = dst[i];
        int slot = atomicAdd(&cur[d >> BSH], 1);
        stage[slot] = make_uint2((unsigned)d, packEdge(src[i], loadF(ew, i, isf32)));
    }
}

// ---------------- phase B: per-bucket -> node-level CSR (start + perm) ----------------
__global__ void __launch_bounds__(256) bucket_place(const uint2* __restrict__ stage,
                                                    const int* __restrict__ bucketStart,
                                                    int* __restrict__ start,
                                                    unsigned* __restrict__ perm) {
    int b = blockIdx.x, tid = threadIdx.x;
    int base = bucketStart[b];
    int cnt = bucketStart[b + 1] - base;
    int n0 = b << BSH;
    int nn = min(256, N_NODES - n0);
    __shared__ int lcnt[256], loff[256], ws[4];
    lcnt[tid] = 0;
    __syncthreads();
    for (int i = tid; i < cnt; i += 256)
        atomicAdd(&lcnt[stage[base + i].x & 255], 1);
    __syncthreads();
    int lane = tid & 63, w = tid >> 6;
    int v = lcnt[tid];
    int sc = v;
#pragma unroll
    for (int o = 1; o < 64; o <<= 1) {
        int t = __shfl_up(sc, o, 64);
        if (lane >= o) sc += t;
    }
    if (lane == 63) ws[w] = sc;
    __syncthreads();
    int woff = 0;
    for (int k = 0; k < w; k++) woff += ws[k];
    loff[tid] = woff + sc - v;
    __syncthreads();
    if (tid < nn) start[n0 + tid] = base + loff[tid];
    if (b == 0 && tid == 0) start[N_NODES] = N_EDGES;
    lcnt[tid] = 0;
    __syncthreads();
    for (int i = tid; i < cnt; i += 256) {
        uint2 sv = stage[base + i];
        int l = sv.x & 255;
        int p = atomicAdd(&lcnt[l], 1);
        perm[base + loff[l] + p] = sv.y;
    }
}

// ---------------- conv1: 8-lanes-per-edge gather + lean epilogue -> x1 -----------------
__global__ void __launch_bounds__(256) conv1_gather(const float* __restrict__ xp1,
                                                    const float* __restrict__ xbn,
                                                    const int* __restrict__ start,
                                                    const unsigned* __restrict__ perm,
                                                    const float* __restrict__ wts,
                                                    float* __restrict__ x1) {
    int lane = threadIdx.x & 63;
    int slot = lane >> 3, f = lane & 7;
    int wid = __builtin_amdgcn_readfirstlane((blockIdx.x * blockDim.x + threadIdx.x) >> 6);
    int nw = (gridDim.x * blockDim.x) >> 6;
    float Wlw[5], Wrw[5];
#pragma unroll
    for (int k = 0; k < 5; k++) {
        Wlw[k] = wts[W_C1LW + k * 64 + lane];
        Wrw[k] = wts[W_C1RW + k * 64 + lane];
    }
    float lb = wts[W_C1LB + lane];
    for (int node = wid; node < N_NODES; node += nw) {
        int e0 = start[node], e1 = start[node + 1];
        float acc = 0.f;
        for (int eb = e0; eb < e1; eb += 32) {
            unsigned p[4];
#pragma unroll
            for (int q = 0; q < 4; q++) {
                int e = eb + q * 8 + slot;
                p[q] = (e < e1) ? perm[e] : 0u;   // sentinel: src 0, w 0
            }
            float v[4];
#pragma unroll
            for (int q = 0; q < 4; q++)
                v[q] = xp1[(size_t)(p[q] >> 15) * 8 + f];
#pragma unroll
            for (int q = 0; q < 4; q++)
                acc += v[q] * edgeW(p[q]);
        }
        acc += __shfl_xor(acc, 8, 64);
        acc += __shfl_xor(acc, 16, 64);
        acc += __shfl_xor(acc, 32, 64);
        float ic = 1.f / fmaxf((float)(e1 - e0), 1.f);
        float xb = (lane < 5) ? xbn[node * 5 + lane] : 0.f;
        float out = lb;
#pragma unroll
        for (int k = 0; k < 5; k++)
            out += RL(acc, k) * ic * Wlw[k] + RL(xb, k) * Wrw[k];
        float ss = out * out;
#pragma unroll
        for (int o = 32; o; o >>= 1) ss += __shfl_xor(ss, o, 64);
        float xv = fmaxf(out / fmaxf(sqrtf(ss), 1e-12f), 0.f);
        x1[(size_t)node * 64 + lane] = xv;
    }
}

// ---------------- proj2: y2 = relu(x1@c2pw+pb)@c2lw, node-blocked (16/wave) -----------
__global__ void __launch_bounds__(256) proj2_blocked(const float* __restrict__ x1,
                                                     const float* __restrict__ wts,
                                                     bf16* __restrict__ y2) {
    int lane = threadIdx.x & 63;
    int wid = (blockIdx.x * blockDim.x + threadIdx.x) >> 6;
    int nb = wid * 16;
    if (nb >= N_NODES) return;
    float xv[16];
#pragma unroll
    for (int n = 0; n < 16; n++) {
        int node = nb + n;
        xv[n] = (node < N_NODES) ? x1[(size_t)node * 64 + lane] : 0.f;
    }
    float a[16];
    float pb = wts[W_C2PB + lane];
#pragma unroll
    for (int n = 0; n < 16; n++) a[n] = pb;
#pragma unroll
    for (int c = 0; c < 4; c++) {
        float Wc[16];
#pragma unroll
        for (int j = 0; j < 16; j++) Wc[j] = wts[W_C2PW + (c * 16 + j) * 64 + lane];
#pragma unroll
        for (int n = 0; n < 16; n++) {
#pragma unroll
            for (int j = 0; j < 16; j++)
                a[n] += RL(xv[n], c * 16 + j) * Wc[j];
        }
    }
#pragma unroll
    for (int n = 0; n < 16; n++) a[n] = fmaxf(a[n], 0.f);
    float b[16];
#pragma unroll
    for (int n = 0; n < 16; n++) b[n] = 0.f;
#pragma unroll
    for (int c = 0; c < 4; c++) {
        float Wc[16];
#pragma unroll
        for (int j = 0; j < 16; j++) Wc[j] = wts[W_C2LW + (c * 16 + j) * 64 + lane];
#pragma unroll
        for (int n = 0; n < 16; n++) {
#pragma unroll
            for (int j = 0; j < 16; j++)
                b[n] += RL(a[n], c * 16 + j) * Wc[j];
        }
    }
#pragma unroll
    for (int n = 0; n < 16; n++) {
        int node = nb + n;
        if (node < N_NODES) y2[(size_t)node * 64 + lane] = __float2bfloat16(b[n]);
    }
}

// ---------------- conv2: gather(bf16, 16-deep) + uint4 perm loads + root + L2norm -----
// Round-9 verdict: phase-windowed variants (r5/r7/r8/r9) all >= 2x slower despite 3.7x
// less FETCH — conv2 is NOT BW-bound; it is VMEM-issue + miss-service limited. This
// version keeps the proven 113us dst-major structure and cuts perm VMEM instructions
// 4x via uint4 loads (perm 16B-aligned in workspace; <=3-edge scalar peel per node).
// NOTE: do NOT fuse more weight matrices in here — latency-bound, lives on occupancy
// (history: +W3[64] => VGPR 84, occ 30%, 199us vs 113us).
__global__ void __launch_bounds__(256) conv2_fused_reg(const bf16* __restrict__ y2,
                                                       const int* __restrict__ start,
                                                       const unsigned* __restrict__ perm,
                                                       const float* __restrict__ x1,
                                                       const float* __restrict__ wts,
                                                       float* __restrict__ x2) {
    int lane = threadIdx.x & 63;
    int wid = __builtin_amdgcn_readfirstlane((blockIdx.x * blockDim.x + threadIdx.x) >> 6);
    int nw = (gridDim.x * blockDim.x) >> 6;
    float W[64];
#pragma unroll
    for (int k = 0; k < 64; k++) W[k] = wts[W_C2RW + k * 64 + lane];
    float lb = wts[W_C2LB + lane];
    for (int node = wid; node < N_NODES; node += nw) {
        int e0 = start[node], e1 = start[node + 1];
        float acc = 0.f;
        int e = e0;
        // peel to 4-edge (16B) alignment — order change only (sum commutative)
        for (; e < e1 && (e & 3); e++) {
            unsigned p = perm[e];
            acc += __bfloat162float(y2[(size_t)edgeSrc(p) * 64 + lane]) * edgeW(p);
        }
        for (; e + 16 <= e1; e += 16) {
            uint4 pa = *(const uint4*)(perm + e);
            uint4 pb = *(const uint4*)(perm + e + 4);
            uint4 pc = *(const uint4*)(perm + e + 8);
            uint4 pd = *(const uint4*)(perm + e + 12);
            unsigned pk[16] = {pa.x, pa.y, pa.z, pa.w, pb.x, pb.y, pb.z, pb.w,
                               pc.x, pc.y, pc.z, pc.w, pd.x, pd.y, pd.z, pd.w};
            float v[16];
#pragma unroll
            for (int u = 0; u < 16; u++)
                v[u] = __bfloat162float(y2[(size_t)edgeSrc(pk[u]) * 64 + lane]);
#pragma unroll
            for (int u = 0; u < 16; u++) acc += v[u] * edgeW(pk[u]);
        }
        for (; e + 4 <= e1; e += 4) {
            uint4 pa = *(const uint4*)(perm + e);
            unsigned pk[4] = {pa.x, pa.y, pa.z, pa.w};
            float v[4];
#pragma unroll
            for (int u = 0; u < 4; u++)
                v[u] = __bfloat162float(y2[(size_t)edgeSrc(pk[u]) * 64 + lane]);
#pragma unroll
            for (int u = 0; u < 4; u++) acc += v[u] * edgeW(pk[u]);
        }
        for (; e < e1; e++) {
            unsigned p = perm[e];
            acc += __bfloat162float(y2[(size_t)edgeSrc(p) * 64 + lane]) * edgeW(p);
        }
        float ic = 1.f / fmaxf((float)(e1 - e0), 1.f);
        float xv = x1[(size_t)node * 64 + lane];
        float o0 = acc * ic + lb, o1 = 0.f, o2 = 0.f, o3 = 0.f;
#pragma unroll
        for (int k = 0; k < 64; k += 4) {
            o0 += RL(xv, k) * W[k];
            o1 += RL(xv, k + 1) * W[k + 1];
            o2 += RL(xv, k + 2) * W[k + 2];
            o3 += RL(xv, k + 3) * W[k + 3];
        }
        float out = (o0 + o1) + (o2 + o3);
        float ss = out * out;
#pragma unroll
        for (int o = 32; o; o >>= 1) ss += __shfl_xor(ss, o, 64);
        float v = out / fmaxf(sqrtf(ss), 1e-12f);
        x2[(size_t)node * 64 + lane] = fmaxf(v, 0.f);
    }
}

// ---------------- conv3 projection, W-in-VGPR: y3 = relu(x2@pw3+pb3)@lw3 (64->5, pad 8) --
__global__ void __launch_bounds__(256) proj3_reg(const float* __restrict__ x2,
                                                 const float* __restrict__ wts,
                                                 float* __restrict__ y3) {
    int lane = threadIdx.x & 63;
    int wid = __builtin_amdgcn_readfirstlane((blockIdx.x * blockDim.x + threadIdx.x) >> 6);
    int nw = (gridDim.x * blockDim.x) >> 6;
    float W1[64], Wl[5];
#pragma unroll
    for (int k = 0; k < 64; k++) W1[k] = wts[W_C3PW + k * 64 + lane];
#pragma unroll
    for (int j = 0; j < 5; j++) Wl[j] = wts[W_C3LW + lane * 5 + j];
    float pb = wts[W_C3PB + lane];
    for (int node = wid; node < N_NODES; node += nw) {
        float xv = x2[(size_t)node * 64 + lane];
        float a0 = pb, a1 = 0.f, a2 = 0.f, a3 = 0.f;
#pragma unroll
        for (int k = 0; k < 64; k += 4) {
            a0 += RL(xv, k) * W1[k];
            a1 += RL(xv, k + 1) * W1[k + 1];
            a2 += RL(xv, k + 2) * W1[k + 2];
            a3 += RL(xv, k + 3) * W1[k + 3];
        }
        float xp = fmaxf((a0 + a1) + (a2 + a3), 0.f);
#pragma unroll
        for (int j = 0; j < 5; j++) {
            float p = xp * Wl[j];
#pragma unroll
            for (int o = 32; o; o >>= 1) p += __shfl_xor(p, o, 64);
            if (lane == j) y3[(size_t)node * 8 + j] = p;
        }
    }
}

// ---------------- conv3: lane-parallel gather (padded rows) + epilogue (no relu) -------
__global__ void __launch_bounds__(256) conv3_fused(const float* __restrict__ y3,
                                                   const float* __restrict__ x2,
                                                   const int* __restrict__ start,
                                                   const unsigned* __restrict__ perm,
                                                   const float* __restrict__ wts,
                                                   const int* __restrict__ flag,
                                                   void* __restrict__ outp) {
    int lane = threadIdx.x & 63;
    int wid = __builtin_amdgcn_readfirstlane((blockIdx.x * blockDim.x + threadIdx.x) >> 6);
    int nw = (gridDim.x * blockDim.x) >> 6;
    float Wr[5];
#pragma unroll
    for (int j = 0; j < 5; j++) Wr[j] = wts[W_C3RW + lane * 5 + j];
    float lb3[5];
#pragma unroll
    for (int j = 0; j < 5; j++) lb3[j] = wts[W_C3LB + j];
    int isf32 = *flag;
    for (int node = wid; node < N_NODES; node += nw) {
        int e0 = start[node], e1 = start[node + 1];
        float s0 = 0, s1 = 0, s2 = 0, s3 = 0, s4 = 0;
        for (int eb = e0; eb < e1; eb += 64) {
            int e = eb + lane;
            if (e < e1) {
                unsigned p = perm[e];
                float w = edgeW(p);
                const float* row = y3 + (size_t)edgeSrc(p) * 8;
                float4 v4 = *(const float4*)row;
                float v5 = row[4];
                s0 += v4.x * w; s1 += v4.y * w; s2 += v4.z * w;
                s3 += v4.w * w; s4 += v5 * w;
            }
        }
#pragma unroll
        for (int o = 32; o; o >>= 1) {
            s0 += __shfl_xor(s0, o, 64);
            s1 += __shfl_xor(s1, o, 64);
            s2 += __shfl_xor(s2, o, 64);
            s3 += __shfl_xor(s3, o, 64);
            s4 += __shfl_xor(s4, o, 64);
        }
        float ic = 1.f / fmaxf((float)(e1 - e0), 1.f);
        float xv = x2[(size_t)node * 64 + lane];
        float m[5] = {s0 * ic, s1 * ic, s2 * ic, s3 * ic, s4 * ic};
        float r[5], ss = 0.f;
#pragma unroll
        for (int j = 0; j < 5; j++) {
            float p = xv * Wr[j];
#pragma unroll
            for (int o = 32; o; o >>= 1) p += __shfl_xor(p, o, 64);
            r[j] = p + m[j] + lb3[j];
            ss += r[j] * r[j];
        }
        float inv = 1.f / fmaxf(sqrtf(ss), 1e-12f);
#pragma unroll
        for (int j = 0; j < 5; j++) {
            if (lane == j) {
                float v = r[j] * inv;
                if (isf32) ((float*)outp)[node * 5 + j] = v;
                else ((bf16*)outp)[node * 5 + j] = __float2bfloat16(v);
            }
        }
    }
}

extern "C" void kernel_launch(void* const* d_in, const int* in_sizes, int n_in,
                              void* d_out, int out_size, void* d_ws, size_t ws_size,
                              hipStream_t stream) {
    const void* h = d_in[0];
    const int* ei = (const int*)d_in[1];
    const int* src = ei;
    const int* dst = ei + N_EDGES;
    const void* ew = d_in[2];

    float* W = (float*)d_ws;
    int* flag = (int*)W;                            // [0]
    float* stats = W + 16;                          // 32 floats
    float* wts = W + 64;                            // ~18k floats
    float* xbn = W + 20480;                         // N*5
    float* xp1 = xbn + N_NODES * 5;                 // N*8 padded (aliased by y3 later)
    int* startp = (int*)(xp1 + N_NODES * 8);        // N+1 ints (+pad)
    int* bucketCnt = startp + N_NODES + 64;         // NB ints
    int* bucketStart = bucketCnt + NB + 1;          // NB+1 ints
    int* bucketCursor = bucketStart + NB + 1;       // NB ints
    // perm word-offset = 1421328 + 391 + 57 = 1421776 ≡ 0 (mod 4) -> 16B-aligned
    unsigned* perm = (unsigned*)(bucketCursor + NB + 57); // E u32 (packed src|w)
    float* x1 = (float*)(perm + N_EDGES);           // N*64 f32
    uint2* stage = (uint2*)x1;                      // E uint2 (dead before x1 written)
    bf16* y2 = (bf16*)(x1 + (size_t)N_NODES * 64);  // N*64 bf16
    float* x2 = x1;                                 // alias: per-thread same-idx read->write
    float* y3 = xp1;                                // alias: xp1 dead after conv1/proj2

    detect_dtype<<<1, 64, 0, stream>>>(ew, flag);
    cvt_weights<<<17, 256, 0, stream>>>(flag,
        d_in[3], d_in[4],
        d_in[5], d_in[6], d_in[7], d_in[8], d_in[9],
        d_in[10], d_in[11], d_in[12], d_in[13], d_in[14],
        d_in[15], d_in[16], d_in[17], d_in[18], d_in[19],
        wts);

    hipMemsetAsync(stats, 0, 32 * sizeof(float), stream);
    hipMemsetAsync(bucketCnt, 0, NB * sizeof(int), stream);

    bn_stats<<<200, 256, 0, stream>>>(h, flag, stats);
    bn_proj1<<<(N_NODES + 255) / 256, 256, 0, stream>>>(h, flag, stats, wts, xbn, xp1);

    // CSR build: bucketed two-phase (no global random-write-through)
    bucket_hist<<<512, 256, 0, stream>>>(dst, bucketCnt);
    bucket_scan<<<1, 512, 0, stream>>>(bucketCnt, bucketStart, bucketCursor);
    bucket_stage<<<512, 256, 0, stream>>>(src, dst, ew, flag, bucketCursor, stage);
    bucket_place<<<NB, 256, 0, stream>>>(stage, bucketStart, startp, perm);

    // conv1: 8-lane-per-edge gather (lean) then blocked projection to y2
    conv1_gather<<<4096, 256, 0, stream>>>(xp1, xbn, startp, perm, wts, x1);
    proj2_blocked<<<(N_NODES / 16 + 1 + 3) / 4, 256, 0, stream>>>(x1, wts, y2);

    // conv2 (latency-bound gather — 16-deep, uint4 perm loads)
    conv2_fused_reg<<<4096, 256, 0, stream>>>(y2, startp, perm, x1, wts, x2);

    // conv3: projection then gather + epilogue
    proj3_reg<<<2048, 256, 0, stream>>>(x2, wts, y3);
    conv3_fused<<<2048, 256, 0, stream>>>(y3, x2, startp, perm, wts, flag, d_out);
}

// Round 13
// 564.963 us; speedup vs baseline: 1.8596x; 1.0164x over previous
//
#include <hip/hip_runtime.h>
#include <hip/hip_bf16.h>

#define N_NODES 100000
#define N_EDGES 3200000
#define BSH 8                         // 256 nodes per bucket
#define NB 391                        // ceil(N_NODES / 256)

typedef __hip_bfloat16 bf16;

// readlane broadcast: float from lane k (k compile-time constant)
#define RL(v, k) __int_as_float(__builtin_amdgcn_readlane(__float_as_int(v), (k)))

// ---- dtype-flexible load: flag==1 -> f32, flag==0 -> bf16 ----
__device__ __forceinline__ float loadF(const void* p, long long i, int isf32) {
    if (isf32) return ((const float*)p)[i];
    unsigned short v = ((const unsigned short*)p)[i];
    union { unsigned u; float f; } c;
    c.u = ((unsigned)v) << 16;
    return c.f;
}

// ---- packed edge: src (17 bits) << 15 | bf16-weight-bits (15 bits; w in [0,1)) ----
__device__ __forceinline__ unsigned packEdge(int s, float w) {
    bf16 b = __float2bfloat16(w);
    unsigned short bits = *(unsigned short*)&b;
    return ((unsigned)s << 15) | (unsigned)(bits & 0x7FFF);
}
__device__ __forceinline__ int edgeSrc(unsigned u) { return (int)(u >> 15); }
__device__ __forceinline__ float edgeW(unsigned u) {
    union { unsigned x; float f; } c;
    c.x = (u & 0x7FFFu) << 16;
    return c.f;
}

// ---- weight canonical layout (float offsets inside wts) ----
#define W_GAMMA 0
#define W_BETA 8
#define W_C1PW 16
#define W_C1PB 48
#define W_C1LW 56
#define W_C1LB 376
#define W_C1RW 440
#define W_C2PW 760
#define W_C2PB 4856
#define W_C2LW 4920
#define W_C2LB 9016
#define W_C2RW 9080
#define W_C3PW 13176
#define W_C3PB 17272
#define W_C3LW 17336
#define W_C3LB 17656
#define W_C3RW 17664

// ---------------- dtype detection ----------------
__global__ void detect_dtype(const void* ew, int* flag) {
    const unsigned short* u = (const unsigned short*)ew;
    int lane = threadIdx.x;
    int big = 0;
    for (int i = lane; i < 1024; i += 64) {
        unsigned short v = u[2 * i];
        int ex = (v >> 7) & 0xFF;
        if (ex >= 128) big++;
    }
#pragma unroll
    for (int o = 32; o; o >>= 1) big += __shfl_xor(big, o, 64);
    if (lane == 0) *flag = (big > 100) ? 1 : 0;
}

// ---------------- convert all weight tensors to canonical fp32 ----------------
__global__ void cvt_weights(const int* flag,
                            const void* p0, const void* p1, const void* p2, const void* p3,
                            const void* p4, const void* p5, const void* p6, const void* p7,
                            const void* p8, const void* p9, const void* p10, const void* p11,
                            const void* p12, const void* p13, const void* p14, const void* p15,
                            const void* p16, float* __restrict__ wts) {
    const void* ptrs[17] = {p0, p1, p2, p3, p4, p5, p6, p7, p8,
                            p9, p10, p11, p12, p13, p14, p15, p16};
    const int sz[17] = {5, 5, 25, 5, 320, 64, 320, 4096, 64,
                        4096, 64, 4096, 4096, 64, 320, 5, 320};
    const int off[17] = {W_GAMMA, W_BETA, W_C1PW, W_C1PB, W_C1LW, W_C1LB, W_C1RW,
                         W_C2PW, W_C2PB, W_C2LW, W_C2LB, W_C2RW,
                         W_C3PW, W_C3PB, W_C3LW, W_C3LB, W_C3RW};
    int t = blockIdx.x;
    int isf32 = *flag;
    for (int i = threadIdx.x; i < sz[t]; i += blockDim.x)
        wts[off[t] + i] = loadF(ptrs[t], i, isf32);
}

// ---------------- BN statistics ----------------
__global__ void bn_stats(const void* __restrict__ h, const int* __restrict__ flag,
                         float* __restrict__ stats) {
    int isf32 = *flag;
    float s[5] = {0, 0, 0, 0, 0}, q[5] = {0, 0, 0, 0, 0};
    int tid = blockIdx.x * blockDim.x + threadIdx.x;
    int stride = gridDim.x * blockDim.x;
    for (int i = tid; i < N_NODES; i += stride) {
#pragma unroll
        for (int f = 0; f < 5; f++) {
            float v = loadF(h, i * 5 + f, isf32);
            s[f] += v;
            q[f] += v * v;
        }
    }
#pragma unroll
    for (int f = 0; f < 5; f++) {
#pragma unroll
        for (int o = 32; o; o >>= 1) {
            s[f] += __shfl_xor(s[f], o, 64);
            q[f] += __shfl_xor(q[f], o, 64);
        }
    }
    __shared__ float ls[4][10];
    int wave = threadIdx.x >> 6, lane = threadIdx.x & 63;
    if (lane == 0) {
#pragma unroll
        for (int f = 0; f < 5; f++) { ls[wave][f] = s[f]; ls[wave][5 + f] = q[f]; }
    }
    __syncthreads();
    if (threadIdx.x < 10) {
        float v = ls[0][threadIdx.x] + ls[1][threadIdx.x] + ls[2][threadIdx.x] + ls[3][threadIdx.x];
        int idx = (threadIdx.x < 5) ? threadIdx.x : (threadIdx.x - 5 + 8);
        atomicAdd(&stats[idx], v);
    }
}

// ---------------- BN finalize + apply + conv1 projection (5->5), fused; xp1 padded to 8 ----
// pad cols 5..7 zeroed (conv1_gather's f>=5 lanes read them)
__global__ void bn_proj1(const void* __restrict__ h, const int* __restrict__ flag,
                         const float* __restrict__ stats, const float* __restrict__ wts,
                         float* __restrict__ xbn, float* __restrict__ xp1) {
    __shared__ float s_sc[5], s_sb[5];
    if (threadIdx.x < 5) {
        int f = threadIdx.x;
        float mean = stats[f] / (float)N_NODES;
        float var = stats[8 + f] / (float)N_NODES - mean * mean;
        float sc = wts[W_GAMMA + f] * rsqrtf(var + 1e-5f);
        s_sc[f] = sc;
        s_sb[f] = wts[W_BETA + f] - mean * sc;
    }
    __syncthreads();
    int isf32 = *flag;
    int i = blockIdx.x * blockDim.x + threadIdx.x;
    if (i >= N_NODES) return;
    float x[5];
#pragma unroll
    for (int f = 0; f < 5; f++)
        x[f] = loadF(h, i * 5 + f, isf32) * s_sc[f] + s_sb[f];
#pragma unroll
    for (int f = 0; f < 5; f++) xbn[i * 5 + f] = x[f];
#pragma unroll
    for (int j = 0; j < 5; j++) {
        float a = wts[W_C1PB + j];
#pragma unroll
        for (int k = 0; k < 5; k++) a += x[k] * wts[W_C1PW + k * 5 + j];
        xp1[i * 8 + j] = fmaxf(a, 0.f);
    }
#pragma unroll
    for (int j = 5; j < 8; j++) xp1[i * 8 + j] = 0.f;
}

// ---------------- CSR build, phase A1: bucket histogram ----------------
__global__ void __launch_bounds__(256) bucket_hist(const int* __restrict__ dst,
                                                   int* __restrict__ bucketCnt) {
    __shared__ int hcnt[NB];
    for (int i = threadIdx.x; i < NB; i += 256) hcnt[i] = 0;
    __syncthreads();
    int per = (N_EDGES + gridDim.x - 1) / gridDim.x;
    int s = blockIdx.x * per;
    int e = min(s + per, N_EDGES);
    for (int i = s + threadIdx.x; i < e; i += 256)
        atomicAdd(&hcnt[dst[i] >> BSH], 1);
    __syncthreads();
    for (int i = threadIdx.x; i < NB; i += 256)
        if (hcnt[i]) atomicAdd(&bucketCnt[i], hcnt[i]);
}

// ---------------- phase A2: exclusive scan of 391 bucket counts ----------------
__global__ void __launch_bounds__(512) bucket_scan(const int* __restrict__ bucketCnt,
                                                   int* __restrict__ bucketStart,
                                                   int* __restrict__ bucketCursor) {
    int tid = threadIdx.x, lane = tid & 63, w = tid >> 6;
    int v = (tid < NB) ? bucketCnt[tid] : 0;
    int sc = v;
#pragma unroll
    for (int o = 1; o < 64; o <<= 1) {
        int t = __shfl_up(sc, o, 64);
        if (lane >= o) sc += t;
    }
    __shared__ int ws[8];
    if (lane == 63) ws[w] = sc;
    __syncthreads();
    if (w == 0) {
        int wv = (lane < 8) ? ws[lane] : 0;
        int s2 = wv;
#pragma unroll
        for (int o = 1; o < 8; o <<= 1) {
            int t = __shfl_up(s2, o, 64);
            if (lane >= o) s2 += t;
        }
        if (lane < 8) ws[lane] = s2;
    }
    __syncthreads();
    int woff = w ? ws[w - 1] : 0;
    int ex = woff + sc - v;
    if (tid < NB) {
        bucketStart[tid] = ex;
        bucketCursor[tid] = ex;
    }
    if (tid == 0) bucketStart[NB] = N_EDGES;
}

// ---------------- phase A3: stage edges bucket-contiguously ({dst, packed}) ----------
__global__ void __launch_bounds__(256) bucket_stage(const int* __restrict__ src,
                                                    const int* __restrict__ dst,
                                                    const void* __restrict__ ew,
                                                    const int* __restrict__ flag,
                                                    int* __restrict__ bucketCursor,
                                                    uint2* __restrict__ stage) {
    __shared__ int hcnt[NB], cur[NB];
    int isf32 = *flag;
    for (int i = threadIdx.x; i < NB; i += 256) hcnt[i] = 0;
    __syncthreads();
    int per = (N_EDGES + gridDim.x - 1) / gridDim.x;
    int s = blockIdx.x * per;
    int e = min(s + per, N_EDGES);
    for (int i = s + threadIdx.x; i < e; i += 256)
        atomicAdd(&hcnt[dst[i] >> BSH], 1);
    __syncthreads();
    for (int i = threadIdx.x; i < NB; i += 256)
        cur[i] = hcnt[i] ? atomicAdd(&bucketCursor[i], hcnt[i]) : 0;
    __syncthreads();
    for (int i = s + threadIdx.x; i < e; i += 256) {
        int d = dst[i];
        int slot = atomicAdd(&cur[d >> BSH], 1);
        stage[slot] = make_uint2((unsigned)d, packEdge(src[i], loadF(ew, i, isf32)));
    }
}

// ---------------- phase B: per-bucket -> node-level CSR (start + perm) ----------------
__global__ void __launch_bounds__(256) bucket_place(const uint2* __restrict__ stage,
                                                    const int* __restrict__ bucketStart,
                                                    int* __restrict__ start,
                                                    unsigned* __restrict__ perm) {
    int b = blockIdx.x, tid = threadIdx.x;
    int base = bucketStart[b];
    int cnt = bucketStart[b + 1] - base;
    int n0 = b << BSH;
    int nn = min(256, N_NODES - n0);
    __shared__ int lcnt[256], loff[256], ws[4];
    lcnt[tid] = 0;
    __syncthreads();
    for (int i = tid; i < cnt; i += 256)
        atomicAdd(&lcnt[stage[base + i].x & 255], 1);
    __syncthreads();
    int lane = tid & 63, w = tid >> 6;
    int v = lcnt[tid];
    int sc = v;
#pragma unroll
    for (int o = 1; o < 64; o <<= 1) {
        int t = __shfl_up(sc, o, 64);
        if (lane >= o) sc += t;
    }
    if (lane == 63) ws[w] = sc;
    __syncthreads();
    int woff = 0;
    for (int k = 0; k < w; k++) woff += ws[k];
    loff[tid] = woff + sc - v;
    __syncthreads();
    if (tid < nn) start[n0 + tid] = base + loff[tid];
    if (b == 0 && tid == 0) start[N_NODES] = N_EDGES;
    lcnt[tid] = 0;
    __syncthreads();
    for (int i = tid; i < cnt; i += 256) {
        uint2 sv = stage[base + i];
        int l = sv.x & 255;
        int p = atomicAdd(&lcnt[l], 1);
        perm[base + loff[l] + p] = sv.y;
    }
}

// ---------------- conv1: 8-lanes-per-edge gather + lean epilogue -> x1 -----------------
__global__ void __launch_bounds__(256) conv1_gather(const float* __restrict__ xp1,
                                                    const float* __restrict__ xbn,
                                                    const int* __restrict__ start,
                                                    const unsigned* __restrict__ perm,
                                                    const float* __restrict__ wts,
                                                    float* __restrict__ x1) {
    int lane = threadIdx.x & 63;
    int slot = lane >> 3, f = lane & 7;
    int wid = __builtin_amdgcn_readfirstlane((blockIdx.x * blockDim.x + threadIdx.x) >> 6);
    int nw = (gridDim.x * blockDim.x) >> 6;
    float Wlw[5], Wrw[5];
#pragma unroll
    for (int k = 0; k < 5; k++) {
        Wlw[k] = wts[W_C1LW + k * 64 + lane];
        Wrw[k] = wts[W_C1RW + k * 64 + lane];
    }
    float lb = wts[W_C1LB + lane];
    for (int node = wid; node < N_NODES; node += nw) {
        int e0 = start[node], e1 = start[node + 1];
        float acc = 0.f;
        for (int eb = e0; eb < e1; eb += 32) {
            unsigned p[4];
#pragma unroll
            for (int q = 0; q < 4; q++) {
                int e = eb + q * 8 + slot;
                p[q] = (e < e1) ? perm[e] : 0u;   // sentinel: src 0, w 0
            }
            float v[4];
#pragma unroll
            for (int q = 0; q < 4; q++)
                v[q] = xp1[(size_t)(p[q] >> 15) * 8 + f];
#pragma unroll
            for (int q = 0; q < 4; q++)
                acc += v[q] * edgeW(p[q]);
        }
        acc += __shfl_xor(acc, 8, 64);
        acc += __shfl_xor(acc, 16, 64);
        acc += __shfl_xor(acc, 32, 64);
        float ic = 1.f / fmaxf((float)(e1 - e0), 1.f);
        float xb = (lane < 5) ? xbn[node * 5 + lane] : 0.f;
        float out = lb;
#pragma unroll
        for (int k = 0; k < 5; k++)
            out += RL(acc, k) * ic * Wlw[k] + RL(xb, k) * Wrw[k];
        float ss = out * out;
#pragma unroll
        for (int o = 32; o; o >>= 1) ss += __shfl_xor(ss, o, 64);
        float xv = fmaxf(out / fmaxf(sqrtf(ss), 1e-12f), 0.f);
        x1[(size_t)node * 64 + lane] = xv;
    }
}

// ---------------- proj2: y2 = relu(x1@c2pw+pb)@c2lw, node-blocked (16/wave) -----------
__global__ void __launch_bounds__(256) proj2_blocked(const float* __restrict__ x1,
                                                     const float* __restrict__ wts,
                                                     bf16* __restrict__ y2) {
    int lane = threadIdx.x & 63;
    int wid = (blockIdx.x * blockDim.x + threadIdx.x) >> 6;
    int nb = wid * 16;
    if (nb >= N_NODES) return;
    float xv[16];
#pragma unroll
    for (int n = 0; n < 16; n++) {
        int node = nb + n;
        xv[n] = (node < N_NODES) ? x1[(size_t)node * 64 + lane] : 0.f;
    }
    float a[16];
    float pb = wts[W_C2PB + lane];
#pragma unroll
    for (int n = 0; n < 16; n++) a[n] = pb;
#pragma unroll
    for (int c = 0; c < 4; c++) {
        float Wc[16];
#pragma unroll
        for (int j = 0; j < 16; j++) Wc[j] = wts[W_C2PW + (c * 16 + j) * 64 + lane];
#pragma unroll
        for (int n = 0; n < 16; n++) {
#pragma unroll
            for (int j = 0; j < 16; j++)
                a[n] += RL(xv[n], c * 16 + j) * Wc[j];
        }
    }
#pragma unroll
    for (int n = 0; n < 16; n++) a[n] = fmaxf(a[n], 0.f);
    float b[16];
#pragma unroll
    for (int n = 0; n < 16; n++) b[n] = 0.f;
#pragma unroll
    for (int c = 0; c < 4; c++) {
        float Wc[16];
#pragma unroll
        for (int j = 0; j < 16; j++) Wc[j] = wts[W_C2LW + (c * 16 + j) * 64 + lane];
#pragma unroll
        for (int n = 0; n < 16; n++) {
#pragma unroll
            for (int j = 0; j < 16; j++)
                b[n] += RL(a[n], c * 16 + j) * Wc[j];
        }
    }
#pragma unroll
    for (int n = 0; n < 16; n++) {
        int node = nb + n;
        if (node < N_NODES) y2[(size_t)node * 64 + lane] = __float2bfloat16(b[n]);
    }
}

// ---------------- conv2: gather(bf16, 16-deep pipelined) + root + L2norm (56 VGPR) ------
// FINAL: the plain 16-deep dst-major gather is the structural optimum. Falsified
// alternatives (this session): deeper/paired ILP (r1/r2), LDS-atomic edge-parallel
// (r3, 10x), phase-windowed gather with/without barrier (r5/r7: 2x despite FETCH
// 312->95MB), virtual-stream batching (r8, spill), materialized phase stream (r9, 2x),
// uint4 perm loads (r12, +14us). conv2 is L2-miss-service bound: ~312MB compulsory
// random-line traffic at ~2.8TB/s effective. Do NOT fuse more weights (occupancy).
__global__ void __launch_bounds__(256) conv2_fused_reg(const bf16* __restrict__ y2,
                                                       const int* __restrict__ start,
                                                       const unsigned* __restrict__ perm,
                                                       const float* __restrict__ x1,
                                                       const float* __restrict__ wts,
                                                       float* __restrict__ x2) {
    int lane = threadIdx.x & 63;
    int wid = __builtin_amdgcn_readfirstlane((blockIdx.x * blockDim.x + threadIdx.x) >> 6);
    int nw = (gridDim.x * blockDim.x) >> 6;
    float W[64];
#pragma unroll
    for (int k = 0; k < 64; k++) W[k] = wts[W_C2RW + k * 64 + lane];
    float lb = wts[W_C2LB + lane];
    for (int node = wid; node < N_NODES; node += nw) {
        int e0 = start[node], e1 = start[node + 1];
        float acc = 0.f;
        int e = e0;
        for (; e + 16 <= e1; e += 16) {
            unsigned p[16];
#pragma unroll
            for (int u = 0; u < 16; u++) p[u] = perm[e + u];
            float v[16];
#pragma unroll
            for (int u = 0; u < 16; u++)
                v[u] = __bfloat162float(y2[(size_t)edgeSrc(p[u]) * 64 + lane]);
#pragma unroll
            for (int u = 0; u < 16; u++) acc += v[u] * edgeW(p[u]);
        }
        for (; e + 4 <= e1; e += 4) {
            unsigned p[4];
#pragma unroll
            for (int u = 0; u < 4; u++) p[u] = perm[e + u];
            float v[4];
#pragma unroll
            for (int u = 0; u < 4; u++)
                v[u] = __bfloat162float(y2[(size_t)edgeSrc(p[u]) * 64 + lane]);
#pragma unroll
            for (int u = 0; u < 4; u++) acc += v[u] * edgeW(p[u]);
        }
        for (; e < e1; e++) {
            unsigned p = perm[e];
            acc += __bfloat162float(y2[(size_t)edgeSrc(p) * 64 + lane]) * edgeW(p);
        }
        float ic = 1.f / fmaxf((float)(e1 - e0), 1.f);
        float xv = x1[(size_t)node * 64 + lane];
        float o0 = acc * ic + lb, o1 = 0.f, o2 = 0.f, o3 = 0.f;
#pragma unroll
        for (int k = 0; k < 64; k += 4) {
            o0 += RL(xv, k) * W[k];
            o1 += RL(xv, k + 1) * W[k + 1];
            o2 += RL(xv, k + 2) * W[k + 2];
            o3 += RL(xv, k + 3) * W[k + 3];
        }
        float out = (o0 + o1) + (o2 + o3);
        float ss = out * out;
#pragma unroll
        for (int o = 32; o; o >>= 1) ss += __shfl_xor(ss, o, 64);
        float v = out / fmaxf(sqrtf(ss), 1e-12f);
        x2[(size_t)node * 64 + lane] = fmaxf(v, 0.f);
    }
}

// ---------------- conv3 projection, W-in-VGPR: y3 = relu(x2@pw3+pb3)@lw3 (64->5, pad 8) --
__global__ void __launch_bounds__(256) proj3_reg(const float* __restrict__ x2,
                                                 const float* __restrict__ wts,
                                                 float* __restrict__ y3) {
    int lane = threadIdx.x & 63;
    int wid = __builtin_amdgcn_readfirstlane((blockIdx.x * blockDim.x + threadIdx.x) >> 6);
    int nw = (gridDim.x * blockDim.x) >> 6;
    float W1[64], Wl[5];
#pragma unroll
    for (int k = 0; k < 64; k++) W1[k] = wts[W_C3PW + k * 64 + lane];
#pragma unroll
    for (int j = 0; j < 5; j++) Wl[j] = wts[W_C3LW + lane * 5 + j];
    float pb = wts[W_C3PB + lane];
    for (int node = wid; node < N_NODES; node += nw) {
        float xv = x2[(size_t)node * 64 + lane];
        float a0 = pb, a1 = 0.f, a2 = 0.f, a3 = 0.f;
#pragma unroll
        for (int k = 0; k < 64; k += 4) {
            a0 += RL(xv, k) * W1[k];
            a1 += RL(xv, k + 1) * W1[k + 1];
            a2 += RL(xv, k + 2) * W1[k + 2];
            a3 += RL(xv, k + 3) * W1[k + 3];
        }
        float xp = fmaxf((a0 + a1) + (a2 + a3), 0.f);
#pragma unroll
        for (int j = 0; j < 5; j++) {
            float p = xp * Wl[j];
#pragma unroll
            for (int o = 32; o; o >>= 1) p += __shfl_xor(p, o, 64);
            if (lane == j) y3[(size_t)node * 8 + j] = p;
        }
    }
}

// ---------------- conv3: lane-parallel gather (padded rows) + epilogue (no relu) -------
__global__ void __launch_bounds__(256) conv3_fused(const float* __restrict__ y3,
                                                   const float* __restrict__ x2,
                                                   const int* __restrict__ start,
                                                   const unsigned* __restrict__ perm,
                                                   const float* __restrict__ wts,
                                                   const int* __restrict__ flag,
                                                   void* __restrict__ outp) {
    int lane = threadIdx.x & 63;
    int wid = __builtin_amdgcn_readfirstlane((blockIdx.x * blockDim.x + threadIdx.x) >> 6);
    int nw = (gridDim.x * blockDim.x) >> 6;
    float Wr[5];
#pragma unroll
    for (int j = 0; j < 5; j++) Wr[j] = wts[W_C3RW + lane * 5 + j];
    float lb3[5];
#pragma unroll
    for (int j = 0; j < 5; j++) lb3[j] = wts[W_C3LB + j];
    int isf32 = *flag;
    for (int node = wid; node < N_NODES; node += nw) {
        int e0 = start[node], e1 = start[node + 1];
        float s0 = 0, s1 = 0, s2 = 0, s3 = 0, s4 = 0;
        for (int eb = e0; eb < e1; eb += 64) {
            int e = eb + lane;
            if (e < e1) {
                unsigned p = perm[e];
                float w = edgeW(p);
                const float* row = y3 + (size_t)edgeSrc(p) * 8;
                float4 v4 = *(const float4*)row;
                float v5 = row[4];
                s0 += v4.x * w; s1 += v4.y * w; s2 += v4.z * w;
                s3 += v4.w * w; s4 += v5 * w;
            }
        }
#pragma unroll
        for (int o = 32; o; o >>= 1) {
            s0 += __shfl_xor(s0, o, 64);
            s1 += __shfl_xor(s1, o, 64);
            s2 += __shfl_xor(s2, o, 64);
            s3 += __shfl_xor(s3, o, 64);
            s4 += __shfl_xor(s4, o, 64);
        }
        float ic = 1.f / fmaxf((float)(e1 - e0), 1.f);
        float xv = x2[(size_t)node * 64 + lane];
        float m[5] = {s0 * ic, s1 * ic, s2 * ic, s3 * ic, s4 * ic};
        float r[5], ss = 0.f;
#pragma unroll
        for (int j = 0; j < 5; j++) {
            float p = xv * Wr[j];
#pragma unroll
            for (int o = 32; o; o >>= 1) p += __shfl_xor(p, o, 64);
            r[j] = p + m[j] + lb3[j];
            ss += r[j] * r[j];
        }
        float inv = 1.f / fmaxf(sqrtf(ss), 1e-12f);
#pragma unroll
        for (int j = 0; j < 5; j++) {
            if (lane == j) {
                float v = r[j] * inv;
                if (isf32) ((float*)outp)[node * 5 + j] = v;
                else ((bf16*)outp)[node * 5 + j] = __float2bfloat16(v);
            }
        }
    }
}

extern "C" void kernel_launch(void* const* d_in, const int* in_sizes, int n_in,
                              void* d_out, int out_size, void* d_ws, size_t ws_size,
                              hipStream_t stream) {
    const void* h = d_in[0];
    const int* ei = (const int*)d_in[1];
    const int* src = ei;
    const int* dst = ei + N_EDGES;
    const void* ew = d_in[2];

    float* W = (float*)d_ws;
    int* flag = (int*)W;                            // [0]
    float* stats = W + 16;                          // 32 floats
    float* wts = W + 64;                            // ~18k floats
    float* xbn = W + 20480;                         // N*5
    float* xp1 = xbn + N_NODES * 5;                 // N*8 padded (aliased by y3 later)
    int* startp = (int*)(xp1 + N_NODES * 8);        // N+1 ints (+pad)
    int* bucketCnt = startp + N_NODES + 64;         // NB ints
    int* bucketStart = bucketCnt + NB + 1;          // NB+1 ints
    int* bucketCursor = bucketStart + NB + 1;       // NB ints
    unsigned* perm = (unsigned*)(bucketCursor + NB + 62); // E u32 (packed src|w)
    float* x1 = (float*)(perm + N_EDGES);           // N*64 f32
    uint2* stage = (uint2*)x1;                      // E uint2 (dead before x1 written)
    bf16* y2 = (bf16*)(x1 + (size_t)N_NODES * 64);  // N*64 bf16
    float* x2 = x1;                                 // alias: per-thread same-idx read->write
    float* y3 = xp1;                                // alias: xp1 dead after conv1/proj2

    detect_dtype<<<1, 64, 0, stream>>>(ew, flag);
    cvt_weights<<<17, 256, 0, stream>>>(flag,
        d_in[3], d_in[4],
        d_in[5], d_in[6], d_in[7], d_in[8], d_in[9],
        d_in[10], d_in[11], d_in[12], d_in[13], d_in[14],
        d_in[15], d_in[16], d_in[17], d_in[18], d_in[19],
        wts);

    hipMemsetAsync(stats, 0, 32 * sizeof(float), stream);
    hipMemsetAsync(bucketCnt, 0, NB * sizeof(int), stream);

    bn_stats<<<200, 256, 0, stream>>>(h, flag, stats);
    bn_proj1<<<(N_NODES + 255) / 256, 256, 0, stream>>>(h, flag, stats, wts, xbn, xp1);

    // CSR build: bucketed two-phase (no global random-write-through)
    bucket_hist<<<512, 256, 0, stream>>>(dst, bucketCnt);
    bucket_scan<<<1, 512, 0, stream>>>(bucketCnt, bucketStart, bucketCursor);
    bucket_stage<<<512, 256, 0, stream>>>(src, dst, ew, flag, bucketCursor, stage);
    bucket_place<<<NB, 256, 0, stream>>>(stage, bucketStart, startp, perm);

    // conv1: 8-lane-per-edge gather (lean) then blocked projection to y2
    conv1_gather<<<4096, 256, 0, stream>>>(xp1, xbn, startp, perm, wts, x1);
    proj2_blocked<<<(N_NODES / 16 + 1 + 3) / 4, 256, 0, stream>>>(x1, wts, y2);

    // conv2 (latency-bound gather — keep lean; proven structural optimum)
    conv2_fused_reg<<<4096, 256, 0, stream>>>(y2, startp, perm, x1, wts, x2);

    // conv3: projection then gather + epilogue
    proj3_reg<<<2048, 256, 0, stream>>>(x2, wts, y3);
    conv3_fused<<<2048, 256, 0, stream>>>(y3, x2, startp, perm, wts, flag, d_out);
}